// Round 1
// baseline (1562.657 us; speedup 1.0000x reference)
//
#include <hip/hip_runtime.h>
#include <hip/hip_bf16.h>

typedef __attribute__((ext_vector_type(8))) short bf16x8;
typedef __attribute__((ext_vector_type(4))) float f32x4;

#define AS1(p) ((const __attribute__((address_space(1))) void*)(p))
#define AS3(p) ((__attribute__((address_space(3))) void*)(p))

// ---------------- conversion / transpose kernels ----------------

__global__ __launch_bounds__(256) void xconv(const float* __restrict__ in,
                                             __hip_bfloat16* __restrict__ out) {
  size_t i = ((size_t)blockIdx.x * 256 + threadIdx.x) * 4;
  float4 v = *(const float4*)(in + i);
  union { __hip_bfloat16 h[4]; ushort4 u; } o;
  o.h[0] = __float2bfloat16(v.x);
  o.h[1] = __float2bfloat16(v.y);
  o.h[2] = __float2bfloat16(v.z);
  o.h[3] = __float2bfloat16(v.w);
  *(ushort4*)(out + i) = o.u;
}

// W [K][N] f32  ->  WT [N][K] bf16
__global__ __launch_bounds__(256) void wtrans(const float* __restrict__ W,
                                              __hip_bfloat16* __restrict__ WT,
                                              int K, int N) {
  __shared__ float t[32][33];
  const int n0 = blockIdx.x << 5, k0 = blockIdx.y << 5;
  const int tx = threadIdx.x, ty = threadIdx.y;
#pragma unroll
  for (int j = 0; j < 4; ++j)
    t[ty + j * 8][tx] = W[(size_t)(k0 + ty + j * 8) * N + n0 + tx];
  __syncthreads();
#pragma unroll
  for (int j = 0; j < 4; ++j)
    WT[(size_t)(n0 + ty + j * 8) * K + k0 + tx] = __float2bfloat16(t[tx][ty + j * 8]);
}

// Vp [B*S][1024] bf16 -> VT [B][8][128][2048] bf16  (per (b,g): VT[d][s] = V[s][d])
__global__ __launch_bounds__(256) void vtrans(const __hip_bfloat16* __restrict__ V,
                                              __hip_bfloat16* __restrict__ VT) {
  __shared__ float t[32][33];
  const int s0 = blockIdx.x << 5, d0 = blockIdx.y << 5;
  const int b = blockIdx.z >> 3, g = blockIdx.z & 7;
  const int tx = threadIdx.x, ty = threadIdx.y;
#pragma unroll
  for (int j = 0; j < 4; ++j)
    t[ty + j * 8][tx] = __bfloat162float(
        V[(size_t)(b * 2048 + s0 + ty + j * 8) * 1024 + g * 128 + d0 + tx]);
  __syncthreads();
#pragma unroll
  for (int j = 0; j < 4; ++j)
    VT[((size_t)(b * 8 + g) * 128 + d0 + ty + j * 8) * 2048 + s0 + tx] =
        __float2bfloat16(t[tx][ty + j * 8]);
}

// RoPE in place on X [4096 rows][H*128], H = 1<<hbits. scale folded (Q: 1/sqrt(128)).
__global__ __launch_bounds__(256) void rope(__hip_bfloat16* __restrict__ X,
                                            const int* __restrict__ pos,
                                            int hbits, float scale) {
  const int t = blockIdx.x * 256 + threadIdx.x;
  const int j = t & 63;
  const int rest = t >> 6;
  const int h = rest & ((1 << hbits) - 1);
  const int row = rest >> hbits;
  const float p = (float)pos[row];
  const float fr = p * exp2f((float)j * -0.2076205059304601f); // 10000^(-j/64)
  float sn, cs;
  __sincosf(fr, &sn, &cs);
  const size_t base = (((size_t)row << hbits) + h) * 128 + j;
  const float x0 = __bfloat162float(X[base]);
  const float x1 = __bfloat162float(X[base + 64]);
  X[base]      = __float2bfloat16((x0 * cs - x1 * sn) * scale);
  X[base + 64] = __float2bfloat16((x1 * cs + x0 * sn) * scale);
}

// ---------------- GEMM: C[M][N] = A[M][K] * BT[N][K]^T  (m97 structure) ----------------

template <int OUT_F32>
__global__ __launch_bounds__(256) void gemm_bt(const __hip_bfloat16* __restrict__ A,
                                               const __hip_bfloat16* __restrict__ BT,
                                               void* __restrict__ Cout,
                                               int M, int N, int K) {
  __shared__ __hip_bfloat16 As[128 * 64];
  __shared__ __hip_bfloat16 Bs[128 * 64];
  const int tid = threadIdx.x;
  const int lane = tid & 63, w = tid >> 6;
  const int m0 = blockIdx.y * 128, n0 = blockIdx.x * 128;
  const int wr = (w >> 1) * 64, wc = (w & 1) * 64;
  const int l15 = lane & 15, lg = lane >> 4;

  f32x4 acc[4][4] = {};

  const int srow = lane >> 3;        // row within 8-row chunk (1 KiB)
  const int scol = (lane & 7) * 8;   // bf16 col within row

  for (int k0 = 0; k0 < K; k0 += 64) {
    __syncthreads();
#pragma unroll
    for (int i = 0; i < 4; ++i) {
      const int chunk = i * 4 + w;               // 16 chunks x 1 KiB
      const int row = chunk * 8 + srow;
      __builtin_amdgcn_global_load_lds(AS1(A + (size_t)(m0 + row) * K + k0 + scol),
                                       AS3(As + chunk * 512), 16, 0, 0);
      __builtin_amdgcn_global_load_lds(AS1(BT + (size_t)(n0 + row) * K + k0 + scol),
                                       AS3(Bs + chunk * 512), 16, 0, 0);
    }
    __syncthreads();
#pragma unroll
    for (int kk = 0; kk < 2; ++kk) {
      bf16x8 af[4], bfr[4];
#pragma unroll
      for (int r = 0; r < 4; ++r) {
        af[r]  = *(const bf16x8*)(As + (wr + r * 16 + l15) * 64 + kk * 32 + lg * 8);
        bfr[r] = *(const bf16x8*)(Bs + (wc + r * 16 + l15) * 64 + kk * 32 + lg * 8);
      }
#pragma unroll
      for (int r = 0; r < 4; ++r)
#pragma unroll
        for (int c = 0; c < 4; ++c)
          acc[r][c] = __builtin_amdgcn_mfma_f32_16x16x32_bf16(af[r], bfr[c], acc[r][c], 0, 0, 0);
    }
  }
  // C/D layout: col = lane&15, row = (lane>>4)*4 + i
#pragma unroll
  for (int r = 0; r < 4; ++r)
#pragma unroll
    for (int c = 0; c < 4; ++c)
#pragma unroll
      for (int i = 0; i < 4; ++i) {
        const size_t row = (size_t)(m0 + wr + r * 16 + lg * 4 + i);
        const size_t col = (size_t)(n0 + wc + c * 16 + l15);
        if (OUT_F32)
          ((float*)Cout)[row * N + col] = acc[r][c][i];
        else
          ((__hip_bfloat16*)Cout)[row * N + col] = __float2bfloat16(acc[r][c][i]);
      }
}

// ---------------- flash attention ----------------
// grid: (qtile 16, head 32, batch 2); 256 threads = 4 waves; each wave owns 32 q rows.
__global__ __launch_bounds__(256) void attn(const __hip_bfloat16* __restrict__ Q,
                                            const __hip_bfloat16* __restrict__ Kp,
                                            const __hip_bfloat16* __restrict__ VT,
                                            __hip_bfloat16* __restrict__ ctx) {
  const int lane = threadIdx.x & 63, w = threadIdx.x >> 6;
  const int l15 = lane & 15, lg = lane >> 4;
  const int qt = blockIdx.x, h = blockIdx.y, b = blockIdx.z;
  const int kvh = h >> 2;
  const int qbase = qt * 128 + w * 32;

  const __hip_bfloat16* Qh = Q + (size_t)b * 2048 * 4096 + h * 128;
  const __hip_bfloat16* Kh = Kp + (size_t)b * 2048 * 1024 + kvh * 128;
  const __hip_bfloat16* Vh = VT + (size_t)(b * 8 + kvh) * 128 * 2048;

  __shared__ __hip_bfloat16 pl[4][32][72];  // per-wave P tile, padded rows (144 B)

  // Q fragments in registers (already scaled by 1/sqrt(128) in rope)
  bf16x8 qf[2][4];
#pragma unroll
  for (int rf = 0; rf < 2; ++rf)
#pragma unroll
    for (int kd = 0; kd < 4; ++kd)
      qf[rf][kd] = *(const bf16x8*)(Qh + (size_t)(qbase + rf * 16 + l15) * 4096 + kd * 32 + lg * 8);

  f32x4 o[2][8] = {};
  float mrun[2][4], lrun[2][4];
#pragma unroll
  for (int rf = 0; rf < 2; ++rf)
#pragma unroll
    for (int i = 0; i < 4; ++i) { mrun[rf][i] = -1e30f; lrun[rf][i] = 0.f; }

  for (int s0 = 0; s0 < 2048; s0 += 64) {
    // S = Q K^T  (pre-scaled)
    f32x4 sc[2][4] = {};
#pragma unroll
    for (int cf = 0; cf < 4; ++cf)
#pragma unroll
      for (int kd = 0; kd < 4; ++kd) {
        bf16x8 kf = *(const bf16x8*)(Kh + (size_t)(s0 + cf * 16 + l15) * 1024 + kd * 32 + lg * 8);
        sc[0][cf] = __builtin_amdgcn_mfma_f32_16x16x32_bf16(qf[0][kd], kf, sc[0][cf], 0, 0, 0);
        sc[1][cf] = __builtin_amdgcn_mfma_f32_16x16x32_bf16(qf[1][kd], kf, sc[1][cf], 0, 0, 0);
      }
    // online softmax (rows live in (lg,i); cols in l15 -> reduce over 16-lane groups)
#pragma unroll
    for (int rf = 0; rf < 2; ++rf)
#pragma unroll
      for (int i = 0; i < 4; ++i) {
        float mx = fmaxf(fmaxf(sc[rf][0][i], sc[rf][1][i]), fmaxf(sc[rf][2][i], sc[rf][3][i]));
        mx = fmaxf(mx, __shfl_xor(mx, 1));
        mx = fmaxf(mx, __shfl_xor(mx, 2));
        mx = fmaxf(mx, __shfl_xor(mx, 4));
        mx = fmaxf(mx, __shfl_xor(mx, 8));
        const float mnew = fmaxf(mrun[rf][i], mx);
        const float fac = __expf(mrun[rf][i] - mnew);
        mrun[rf][i] = mnew;
        float rs = 0.f;
#pragma unroll
        for (int cf = 0; cf < 4; ++cf) {
          const float p = __expf(sc[rf][cf][i] - mnew);
          sc[rf][cf][i] = p;
          rs += p;
        }
        rs += __shfl_xor(rs, 1);
        rs += __shfl_xor(rs, 2);
        rs += __shfl_xor(rs, 4);
        rs += __shfl_xor(rs, 8);
        lrun[rf][i] = lrun[rf][i] * fac + rs;
#pragma unroll
        for (int d = 0; d < 8; ++d) o[rf][d][i] *= fac;
#pragma unroll
        for (int cf = 0; cf < 4; ++cf)
          pl[w][rf * 16 + lg * 4 + i][cf * 16 + l15] = __float2bfloat16(sc[rf][cf][i]);
      }
    // P -> A-fragments (same-wave LDS RAW: DS ops complete in order within a wave)
    bf16x8 pa[2][2];
#pragma unroll
    for (int rf = 0; rf < 2; ++rf)
#pragma unroll
      for (int kk = 0; kk < 2; ++kk)
        pa[rf][kk] = *(const bf16x8*)&pl[w][rf * 16 + l15][kk * 32 + lg * 8];
    // O += P V
#pragma unroll
    for (int d = 0; d < 8; ++d)
#pragma unroll
      for (int kk = 0; kk < 2; ++kk) {
        bf16x8 vf = *(const bf16x8*)(Vh + (size_t)(d * 16 + l15) * 2048 + s0 + kk * 32 + lg * 8);
        o[0][d] = __builtin_amdgcn_mfma_f32_16x16x32_bf16(pa[0][kk], vf, o[0][d], 0, 0, 0);
        o[1][d] = __builtin_amdgcn_mfma_f32_16x16x32_bf16(pa[1][kk], vf, o[1][d], 0, 0, 0);
      }
  }
  // normalize + write ctx [B*S][4096]
#pragma unroll
  for (int rf = 0; rf < 2; ++rf)
#pragma unroll
    for (int i = 0; i < 4; ++i) {
      const float inv = 1.0f / lrun[rf][i];
      const size_t row = (size_t)b * 2048 + qbase + rf * 16 + lg * 4 + i;
#pragma unroll
      for (int d = 0; d < 8; ++d)
        ctx[row * 4096 + h * 128 + d * 16 + l15] = __float2bfloat16(o[rf][d][i] * inv);
    }
}

// ---------------- launcher ----------------

extern "C" void kernel_launch(void* const* d_in, const int* in_sizes, int n_in,
                              void* d_out, int out_size, void* d_ws, size_t ws_size,
                              hipStream_t stream) {
  const float* q_in = (const float*)d_in[0];
  const float* k_in = (const float*)d_in[1];
  const float* v_in = (const float*)d_in[2];
  const int* pos    = (const int*)d_in[3];
  const float* Wq   = (const float*)d_in[4];
  const float* Wk   = (const float*)d_in[5];
  const float* Wv   = (const float*)d_in[6];
  const float* Wo   = (const float*)d_in[7];

  char* ws = (char*)d_ws;
  // layout (bytes): total 176,160,768
  __hip_bfloat16* xbuf = (__hip_bfloat16*)(ws);              // 33.5 MB, reused as ctx
  __hip_bfloat16* WqT  = (__hip_bfloat16*)(ws + 33554432);   // 33.5 MB
  __hip_bfloat16* WkT  = (__hip_bfloat16*)(ws + 67108864);   // 8.4 MB
  __hip_bfloat16* WvT  = (__hip_bfloat16*)(ws + 75497472);   // 8.4 MB
  __hip_bfloat16* WoT  = (__hip_bfloat16*)(ws + 83886080);   // 33.5 MB
  __hip_bfloat16* Qp   = (__hip_bfloat16*)(ws + 117440512);  // 33.5 MB
  __hip_bfloat16* Kp   = (__hip_bfloat16*)(ws + 150994944);  // 8.4 MB
  __hip_bfloat16* Vp   = (__hip_bfloat16*)(ws + 159383552);  // 8.4 MB
  __hip_bfloat16* VTb  = (__hip_bfloat16*)(ws + 167772160);  // 8.4 MB

  const dim3 tb(32, 8);
  wtrans<<<dim3(128, 128), tb, 0, stream>>>(Wq, WqT, 4096, 4096);
  wtrans<<<dim3(32, 128),  tb, 0, stream>>>(Wk, WkT, 4096, 1024);
  wtrans<<<dim3(32, 128),  tb, 0, stream>>>(Wv, WvT, 4096, 1024);
  wtrans<<<dim3(128, 128), tb, 0, stream>>>(Wo, WoT, 4096, 4096);

  // Q path
  xconv<<<16384, 256, 0, stream>>>(q_in, xbuf);
  gemm_bt<0><<<dim3(32, 32), 256, 0, stream>>>(xbuf, WqT, Qp, 4096, 4096, 4096);
  rope<<<32768, 256, 0, stream>>>(Qp, pos, 5, 0.08838834764831845f); // 1/sqrt(128)
  // K path
  xconv<<<16384, 256, 0, stream>>>(k_in, xbuf);
  gemm_bt<0><<<dim3(8, 32), 256, 0, stream>>>(xbuf, WkT, Kp, 4096, 1024, 4096);
  rope<<<8192, 256, 0, stream>>>(Kp, pos, 3, 1.0f);
  // V path
  xconv<<<16384, 256, 0, stream>>>(v_in, xbuf);
  gemm_bt<0><<<dim3(8, 32), 256, 0, stream>>>(xbuf, WvT, Vp, 4096, 1024, 4096);
  vtrans<<<dim3(64, 4, 16), tb, 0, stream>>>(Vp, VTb);

  // attention -> ctx (reuses xbuf; all three xconv consumers are done)
  attn<<<dim3(16, 32, 2), 256, 0, stream>>>(Qp, Kp, VTb, xbuf);

  // output projection, f32 epilogue straight to d_out
  gemm_bt<1><<<dim3(32, 32), 256, 0, stream>>>(xbuf, WoT, d_out, 4096, 4096, 4096);
}

// Round 2
// 1184.970 us; speedup vs baseline: 1.3187x; 1.3187x over previous
//
#include <hip/hip_runtime.h>
#include <hip/hip_bf16.h>

typedef __attribute__((ext_vector_type(8))) short bf16x8;
typedef __attribute__((ext_vector_type(4))) float f32x4;

#define AS1(p) ((const __attribute__((address_space(1))) void*)(p))
#define AS3(p) ((__attribute__((address_space(3))) void*)(p))

// ---------------- conversion / transpose kernels ----------------

__global__ __launch_bounds__(256) void xconv(const float* __restrict__ in,
                                             __hip_bfloat16* __restrict__ out) {
  size_t i = ((size_t)blockIdx.x * 256 + threadIdx.x) * 4;
  float4 v = *(const float4*)(in + i);
  union { __hip_bfloat16 h[4]; ushort4 u; } o;
  o.h[0] = __float2bfloat16(v.x);
  o.h[1] = __float2bfloat16(v.y);
  o.h[2] = __float2bfloat16(v.z);
  o.h[3] = __float2bfloat16(v.w);
  *(ushort4*)(out + i) = o.u;
}

// W [K][N] f32  ->  WT [N][K] bf16
__global__ __launch_bounds__(256) void wtrans(const float* __restrict__ W,
                                              __hip_bfloat16* __restrict__ WT,
                                              int K, int N) {
  __shared__ float t[32][33];
  const int n0 = blockIdx.x << 5, k0 = blockIdx.y << 5;
  const int tx = threadIdx.x, ty = threadIdx.y;
#pragma unroll
  for (int j = 0; j < 4; ++j)
    t[ty + j * 8][tx] = W[(size_t)(k0 + ty + j * 8) * N + n0 + tx];
  __syncthreads();
#pragma unroll
  for (int j = 0; j < 4; ++j)
    WT[(size_t)(n0 + ty + j * 8) * K + k0 + tx] = __float2bfloat16(t[tx][ty + j * 8]);
}

// Vp [B*S][1024] bf16 -> VT [B][8][128][2048] bf16  (per (b,g): VT[d][s] = V[s][d])
__global__ __launch_bounds__(256) void vtrans(const __hip_bfloat16* __restrict__ V,
                                              __hip_bfloat16* __restrict__ VT) {
  __shared__ float t[32][33];
  const int s0 = blockIdx.x << 5, d0 = blockIdx.y << 5;
  const int b = blockIdx.z >> 3, g = blockIdx.z & 7;
  const int tx = threadIdx.x, ty = threadIdx.y;
#pragma unroll
  for (int j = 0; j < 4; ++j)
    t[ty + j * 8][tx] = __bfloat162float(
        V[(size_t)(b * 2048 + s0 + ty + j * 8) * 1024 + g * 128 + d0 + tx]);
  __syncthreads();
#pragma unroll
  for (int j = 0; j < 4; ++j)
    VT[((size_t)(b * 8 + g) * 128 + d0 + ty + j * 8) * 2048 + s0 + tx] =
        __float2bfloat16(t[tx][ty + j * 8]);
}

// RoPE in place on X [4096 rows][H*128], H = 1<<hbits. scale folded (Q: 1/sqrt(128)).
__global__ __launch_bounds__(256) void rope(__hip_bfloat16* __restrict__ X,
                                            const int* __restrict__ pos,
                                            int hbits, float scale) {
  const int t = blockIdx.x * 256 + threadIdx.x;
  const int j = t & 63;
  const int rest = t >> 6;
  const int h = rest & ((1 << hbits) - 1);
  const int row = rest >> hbits;
  const float p = (float)pos[row];
  const float fr = p * exp2f((float)j * -0.2076205059304601f); // 10000^(-j/64)
  float sn, cs;
  __sincosf(fr, &sn, &cs);
  const size_t base = (((size_t)row << hbits) + h) * 128 + j;
  const float x0 = __bfloat162float(X[base]);
  const float x1 = __bfloat162float(X[base + 64]);
  X[base]      = __float2bfloat16((x0 * cs - x1 * sn) * scale);
  X[base + 64] = __float2bfloat16((x1 * cs + x0 * sn) * scale);
}

// ---------------- GEMM: C[M][N] = A[M][K] * BT[N][K]^T  (m97 structure) ----------------

template <int OUT_F32>
__global__ __launch_bounds__(256) void gemm_bt(const __hip_bfloat16* __restrict__ A,
                                               const __hip_bfloat16* __restrict__ BT,
                                               void* __restrict__ Cout,
                                               int M, int N, int K) {
  __shared__ __hip_bfloat16 As[128 * 64];
  __shared__ __hip_bfloat16 Bs[128 * 64];
  const int tid = threadIdx.x;
  const int lane = tid & 63, w = tid >> 6;
  const int m0 = blockIdx.y * 128, n0 = blockIdx.x * 128;
  const int wr = (w >> 1) * 64, wc = (w & 1) * 64;
  const int l15 = lane & 15, lg = lane >> 4;

  f32x4 acc[4][4] = {};

  const int srow = lane >> 3;        // row within 8-row chunk (1 KiB)
  const int scol = (lane & 7) * 8;   // bf16 col within row

  for (int k0 = 0; k0 < K; k0 += 64) {
    __syncthreads();
#pragma unroll
    for (int i = 0; i < 4; ++i) {
      const int chunk = i * 4 + w;               // 16 chunks x 1 KiB
      const int row = chunk * 8 + srow;
      __builtin_amdgcn_global_load_lds(AS1(A + (size_t)(m0 + row) * K + k0 + scol),
                                       AS3(As + chunk * 512), 16, 0, 0);
      __builtin_amdgcn_global_load_lds(AS1(BT + (size_t)(n0 + row) * K + k0 + scol),
                                       AS3(Bs + chunk * 512), 16, 0, 0);
    }
    __syncthreads();
#pragma unroll
    for (int kk = 0; kk < 2; ++kk) {
      bf16x8 af[4], bfr[4];
#pragma unroll
      for (int r = 0; r < 4; ++r) {
        af[r]  = *(const bf16x8*)(As + (wr + r * 16 + l15) * 64 + kk * 32 + lg * 8);
        bfr[r] = *(const bf16x8*)(Bs + (wc + r * 16 + l15) * 64 + kk * 32 + lg * 8);
      }
#pragma unroll
      for (int r = 0; r < 4; ++r)
#pragma unroll
        for (int c = 0; c < 4; ++c)
          acc[r][c] = __builtin_amdgcn_mfma_f32_16x16x32_bf16(af[r], bfr[c], acc[r][c], 0, 0, 0);
    }
  }
  // C/D layout: col = lane&15, row = (lane>>4)*4 + i
#pragma unroll
  for (int r = 0; r < 4; ++r)
#pragma unroll
    for (int c = 0; c < 4; ++c)
#pragma unroll
      for (int i = 0; i < 4; ++i) {
        const size_t row = (size_t)(m0 + wr + r * 16 + lg * 4 + i);
        const size_t col = (size_t)(n0 + wc + c * 16 + l15);
        if (OUT_F32)
          ((float*)Cout)[row * N + col] = acc[r][c][i];
        else
          ((__hip_bfloat16*)Cout)[row * N + col] = __float2bfloat16(acc[r][c][i]);
      }
}

// ---------------- flash attention (2-phase LDS-staged, XOR-swizzled) ----------------
// grid: (qtile 16, head 32, batch 2); 256 threads = 4 waves; each wave owns 32 q rows.
// LDS: K tile 64x128 (dbuf) + VT tile 128x64 (dbuf) + P round-trip = 80 KB -> 2 blocks/CU.
__global__ __launch_bounds__(256) void attn(const __hip_bfloat16* __restrict__ Q,
                                            const __hip_bfloat16* __restrict__ Kp,
                                            const __hip_bfloat16* __restrict__ VT,
                                            __hip_bfloat16* __restrict__ ctx) {
  const int lane = threadIdx.x & 63, w = threadIdx.x >> 6;
  const int l15 = lane & 15, lg = lane >> 4;
  const int qt = blockIdx.x, h = blockIdx.y, b = blockIdx.z;
  const int kvh = h >> 2;
  const int qbase = qt * 128 + w * 32;

  const __hip_bfloat16* Qh = Q + (size_t)b * 2048 * 4096 + h * 128;
  const __hip_bfloat16* Kh = Kp + (size_t)b * 2048 * 1024 + kvh * 128;
  const __hip_bfloat16* Vh = VT + (size_t)(b * 8 + kvh) * 128 * 2048;

  __shared__ __hip_bfloat16 Ks[2][64 * 128];   // [s][d], rows 256B, XOR-swizzled
  __shared__ __hip_bfloat16 Vs[2][128 * 64];   // [d][s], rows 128B, XOR-swizzled
  __shared__ __hip_bfloat16 pl[4][32 * 64];    // per-wave P tile, XOR-swizzled

  // Staging: linear LDS dest (wave-uniform base + lane*16B), inverse-swizzled
  // global source; ds_read applies the same XOR (both-sides rule).
  auto stage = [&](int buf, int s0) {
#pragma unroll
    for (int i = 0; i < 4; ++i) {
      const int chunk = i * 4 + w;                 // 16 x 1KiB per tile
      // K: 1KiB = 4 rows x 256B; lane: row=chunk*4+(lane>>4), c16=lane&15
      const int rK = chunk * 4 + (lane >> 4);
      const int cK = (lane & 15) ^ (rK & 7);
      __builtin_amdgcn_global_load_lds(AS1(Kh + (size_t)(s0 + rK) * 1024 + cK * 8),
                                       AS3(&Ks[buf][chunk * 512]), 16, 0, 0);
      // V: 1KiB = 8 rows x 128B; lane: row=chunk*8+(lane>>3), c8=lane&7
      const int rV = chunk * 8 + (lane >> 3);
      const int cV = (lane & 7) ^ (rV & 7);
      __builtin_amdgcn_global_load_lds(AS1(Vh + (size_t)rV * 2048 + s0 + cV * 8),
                                       AS3(&Vs[buf][chunk * 512]), 16, 0, 0);
    }
  };

  // Q fragments in registers (already scaled by 1/sqrt(128) in rope)
  bf16x8 qf[2][4];
#pragma unroll
  for (int rf = 0; rf < 2; ++rf)
#pragma unroll
    for (int kd = 0; kd < 4; ++kd)
      qf[rf][kd] = *(const bf16x8*)(Qh + (size_t)(qbase + rf * 16 + l15) * 4096 + kd * 32 + lg * 8);

  f32x4 o[2][8] = {};
  float mrun[2][4], lrun[2][4];
#pragma unroll
  for (int rf = 0; rf < 2; ++rf)
#pragma unroll
    for (int i = 0; i < 4; ++i) { mrun[rf][i] = -1e30f; lrun[rf][i] = 0.f; }

  stage(0, 0);
  __syncthreads();

  for (int t = 0; t < 32; ++t) {
    const int cur = t & 1;
    if (t + 1 < 32) stage(cur ^ 1, (t + 1) * 64);   // prefetch lands under compute

    // S = Q K^T from LDS (swizzled reads)
    f32x4 sc[2][4] = {};
#pragma unroll
    for (int cf = 0; cf < 4; ++cf)
#pragma unroll
      for (int kd = 0; kd < 4; ++kd) {
        const int row = cf * 16 + l15;
        const int c16 = (kd * 4 + lg) ^ (row & 7);
        bf16x8 kf = *(const bf16x8*)(&Ks[cur][row * 128 + c16 * 8]);
        sc[0][cf] = __builtin_amdgcn_mfma_f32_16x16x32_bf16(qf[0][kd], kf, sc[0][cf], 0, 0, 0);
        sc[1][cf] = __builtin_amdgcn_mfma_f32_16x16x32_bf16(qf[1][kd], kf, sc[1][cf], 0, 0, 0);
      }
    // online softmax (rows live in (lg,i); cols in l15 -> reduce over 16-lane groups)
#pragma unroll
    for (int rf = 0; rf < 2; ++rf)
#pragma unroll
      for (int i = 0; i < 4; ++i) {
        float mx = fmaxf(fmaxf(sc[rf][0][i], sc[rf][1][i]), fmaxf(sc[rf][2][i], sc[rf][3][i]));
        mx = fmaxf(mx, __shfl_xor(mx, 1));
        mx = fmaxf(mx, __shfl_xor(mx, 2));
        mx = fmaxf(mx, __shfl_xor(mx, 4));
        mx = fmaxf(mx, __shfl_xor(mx, 8));
        const float mnew = fmaxf(mrun[rf][i], mx);
        const float fac = __expf(mrun[rf][i] - mnew);
        mrun[rf][i] = mnew;
        float rs = 0.f;
#pragma unroll
        for (int cf = 0; cf < 4; ++cf) {
          const float p = __expf(sc[rf][cf][i] - mnew);
          sc[rf][cf][i] = p;
          rs += p;
        }
        rs += __shfl_xor(rs, 1);
        rs += __shfl_xor(rs, 2);
        rs += __shfl_xor(rs, 4);
        rs += __shfl_xor(rs, 8);
        lrun[rf][i] = lrun[rf][i] * fac + rs;
#pragma unroll
        for (int d = 0; d < 8; ++d) o[rf][d][i] *= fac;
        // P store: bf16 idx = row*64 + ((cf*16+l15) ^ ((row&7)<<3))
        const int rowp = rf * 16 + lg * 4 + i;
#pragma unroll
        for (int cf = 0; cf < 4; ++cf)
          pl[w][rowp * 64 + ((cf * 16 + l15) ^ ((rowp & 7) << 3))] =
              __float2bfloat16(sc[rf][cf][i]);
      }
    // P -> A-fragments (same-wave LDS RAW: DS ops complete in order within a wave)
    bf16x8 pa[2][2];
#pragma unroll
    for (int rf = 0; rf < 2; ++rf)
#pragma unroll
      for (int kk = 0; kk < 2; ++kk) {
        const int rowp = rf * 16 + l15;
        pa[rf][kk] = *(const bf16x8*)(&pl[w][rowp * 64 + ((kk * 32 + lg * 8) ^ ((rowp & 7) << 3))]);
      }
    // O += P V from LDS (swizzled reads)
#pragma unroll
    for (int d = 0; d < 8; ++d)
#pragma unroll
      for (int kk = 0; kk < 2; ++kk) {
        const int rowv = d * 16 + l15;
        const int c8 = (kk * 4 + lg) ^ (rowv & 7);
        bf16x8 vf = *(const bf16x8*)(&Vs[cur][rowv * 64 + c8 * 8]);
        o[0][d] = __builtin_amdgcn_mfma_f32_16x16x32_bf16(pa[0][kk], vf, o[0][d], 0, 0, 0);
        o[1][d] = __builtin_amdgcn_mfma_f32_16x16x32_bf16(pa[1][kk], vf, o[1][d], 0, 0, 0);
      }
    __syncthreads();   // drains prefetch vmcnt + pl/V ds ops; swaps buffers
  }
  // normalize + write ctx [B*S][4096]
#pragma unroll
  for (int rf = 0; rf < 2; ++rf)
#pragma unroll
    for (int i = 0; i < 4; ++i) {
      const float inv = 1.0f / lrun[rf][i];
      const size_t row = (size_t)b * 2048 + qbase + rf * 16 + lg * 4 + i;
#pragma unroll
      for (int d = 0; d < 8; ++d)
        ctx[row * 4096 + h * 128 + d * 16 + l15] = __float2bfloat16(o[rf][d][i] * inv);
    }
}

// ---------------- launcher ----------------

extern "C" void kernel_launch(void* const* d_in, const int* in_sizes, int n_in,
                              void* d_out, int out_size, void* d_ws, size_t ws_size,
                              hipStream_t stream) {
  const float* q_in = (const float*)d_in[0];
  const float* k_in = (const float*)d_in[1];
  const float* v_in = (const float*)d_in[2];
  const int* pos    = (const int*)d_in[3];
  const float* Wq   = (const float*)d_in[4];
  const float* Wk   = (const float*)d_in[5];
  const float* Wv   = (const float*)d_in[6];
  const float* Wo   = (const float*)d_in[7];

  char* ws = (char*)d_ws;
  __hip_bfloat16* xbuf = (__hip_bfloat16*)(ws);              // 33.5 MB, reused as ctx
  __hip_bfloat16* WqT  = (__hip_bfloat16*)(ws + 33554432);   // 33.5 MB
  __hip_bfloat16* WkT  = (__hip_bfloat16*)(ws + 67108864);   // 8.4 MB
  __hip_bfloat16* WvT  = (__hip_bfloat16*)(ws + 75497472);   // 8.4 MB
  __hip_bfloat16* WoT  = (__hip_bfloat16*)(ws + 83886080);   // 33.5 MB
  __hip_bfloat16* Qp   = (__hip_bfloat16*)(ws + 117440512);  // 33.5 MB
  __hip_bfloat16* Kp   = (__hip_bfloat16*)(ws + 150994944);  // 8.4 MB
  __hip_bfloat16* Vp   = (__hip_bfloat16*)(ws + 159383552);  // 8.4 MB
  __hip_bfloat16* VTb  = (__hip_bfloat16*)(ws + 167772160);  // 8.4 MB

  const dim3 tb(32, 8);
  wtrans<<<dim3(128, 128), tb, 0, stream>>>(Wq, WqT, 4096, 4096);
  wtrans<<<dim3(32, 128),  tb, 0, stream>>>(Wk, WkT, 4096, 1024);
  wtrans<<<dim3(32, 128),  tb, 0, stream>>>(Wv, WvT, 4096, 1024);
  wtrans<<<dim3(128, 128), tb, 0, stream>>>(Wo, WoT, 4096, 4096);

  // Q path
  xconv<<<16384, 256, 0, stream>>>(q_in, xbuf);
  gemm_bt<0><<<dim3(32, 32), 256, 0, stream>>>(xbuf, WqT, Qp, 4096, 4096, 4096);
  rope<<<32768, 256, 0, stream>>>(Qp, pos, 5, 0.08838834764831845f); // 1/sqrt(128)
  // K path
  xconv<<<16384, 256, 0, stream>>>(k_in, xbuf);
  gemm_bt<0><<<dim3(8, 32), 256, 0, stream>>>(xbuf, WkT, Kp, 4096, 1024, 4096);
  rope<<<8192, 256, 0, stream>>>(Kp, pos, 3, 1.0f);
  // V path
  xconv<<<16384, 256, 0, stream>>>(v_in, xbuf);
  gemm_bt<0><<<dim3(8, 32), 256, 0, stream>>>(xbuf, WvT, Vp, 4096, 1024, 4096);
  vtrans<<<dim3(64, 4, 16), tb, 0, stream>>>(Vp, VTb);

  // attention -> ctx (reuses xbuf; all three xconv consumers are done)
  attn<<<dim3(16, 32, 2), 256, 0, stream>>>(Qp, Kp, VTb, xbuf);

  // output projection, f32 epilogue straight to d_out
  gemm_bt<1><<<dim3(32, 32), 256, 0, stream>>>(xbuf, WoT, d_out, 4096, 4096, 4096);
}

// Round 4
// 951.051 us; speedup vs baseline: 1.6431x; 1.2460x over previous
//
#include <hip/hip_runtime.h>
#include <hip/hip_bf16.h>

typedef __attribute__((ext_vector_type(8))) short bf16x8;
typedef __attribute__((ext_vector_type(4))) float f32x4;
typedef __attribute__((ext_vector_type(16))) float f32x16;
typedef __attribute__((ext_vector_type(2))) unsigned uint2x;

#define AS1(p) ((const __attribute__((address_space(1))) void*)(p))
#define AS3(p) ((__attribute__((address_space(3))) void*)(p))

__device__ inline unsigned cvtpk_bf16(float lo, float hi) {
  unsigned r;
  asm("v_cvt_pk_bf16_f32 %0, %1, %2" : "=v"(r) : "v"(lo), "v"(hi));
  return r;
}

// permlane32_swap via builtin (proper dataflow; inline-asm "+v","+v" with identical
// inputs risked operand coalescing -> v_permlane32_swap v5,v5 -> broken reduce).
// returns {[a_lo|b_lo], [a_hi|b_hi]} (lane halves exchanged between the two regs)
__device__ inline uint2x plswap(unsigned a, unsigned b) {
  return __builtin_amdgcn_permlane32_swap(a, b, false, false);
}

// ---------------- conversion / transpose kernels ----------------

__global__ __launch_bounds__(256) void xconv(const float* __restrict__ in,
                                             __hip_bfloat16* __restrict__ out) {
  size_t i = ((size_t)blockIdx.x * 256 + threadIdx.x) * 4;
  float4 v = *(const float4*)(in + i);
  union { __hip_bfloat16 h[4]; ushort4 u; } o;
  o.h[0] = __float2bfloat16(v.x);
  o.h[1] = __float2bfloat16(v.y);
  o.h[2] = __float2bfloat16(v.z);
  o.h[3] = __float2bfloat16(v.w);
  *(ushort4*)(out + i) = o.u;
}

// W [K][N] f32  ->  WT [N][K] bf16
__global__ __launch_bounds__(256) void wtrans(const float* __restrict__ W,
                                              __hip_bfloat16* __restrict__ WT,
                                              int K, int N) {
  __shared__ float t[32][33];
  const int n0 = blockIdx.x << 5, k0 = blockIdx.y << 5;
  const int tx = threadIdx.x, ty = threadIdx.y;
#pragma unroll
  for (int j = 0; j < 4; ++j)
    t[ty + j * 8][tx] = W[(size_t)(k0 + ty + j * 8) * N + n0 + tx];
  __syncthreads();
#pragma unroll
  for (int j = 0; j < 4; ++j)
    WT[(size_t)(n0 + ty + j * 8) * K + k0 + tx] = __float2bfloat16(t[tx][ty + j * 8]);
}

// Vp [B*S][1024] bf16 -> VT [B][8][128][2048] bf16  (per (b,g): VT[d][s] = V[s][d])
__global__ __launch_bounds__(256) void vtrans(const __hip_bfloat16* __restrict__ V,
                                              __hip_bfloat16* __restrict__ VT) {
  __shared__ float t[32][33];
  const int s0 = blockIdx.x << 5, d0 = blockIdx.y << 5;
  const int b = blockIdx.z >> 3, g = blockIdx.z & 7;
  const int tx = threadIdx.x, ty = threadIdx.y;
#pragma unroll
  for (int j = 0; j < 4; ++j)
    t[ty + j * 8][tx] = __bfloat162float(
        V[(size_t)(b * 2048 + s0 + ty + j * 8) * 1024 + g * 128 + d0 + tx]);
  __syncthreads();
#pragma unroll
  for (int j = 0; j < 4; ++j)
    VT[((size_t)(b * 8 + g) * 128 + d0 + ty + j * 8) * 2048 + s0 + tx] =
        __float2bfloat16(t[tx][ty + j * 8]);
}

// RoPE in place on X [4096 rows][H*128], H = 1<<hbits. scale folded.
__global__ __launch_bounds__(256) void rope(__hip_bfloat16* __restrict__ X,
                                            const int* __restrict__ pos,
                                            int hbits, float scale) {
  const int t = blockIdx.x * 256 + threadIdx.x;
  const int j = t & 63;
  const int rest = t >> 6;
  const int h = rest & ((1 << hbits) - 1);
  const int row = rest >> hbits;
  const float p = (float)pos[row];
  const float fr = p * exp2f((float)j * -0.2076205059304601f); // 10000^(-j/64)
  float sn, cs;
  __sincosf(fr, &sn, &cs);
  const size_t base = (((size_t)row << hbits) + h) * 128 + j;
  const float x0 = __bfloat162float(X[base]);
  const float x1 = __bfloat162float(X[base + 64]);
  X[base]      = __float2bfloat16((x0 * cs - x1 * sn) * scale);
  X[base + 64] = __float2bfloat16((x1 * cs + x0 * sn) * scale);
}

// ---------------- GEMM: C[M][N] = A[M][K] * BT[N][K]^T  (m97 structure) ----------------

template <int OUT_F32>
__global__ __launch_bounds__(256) void gemm_bt(const __hip_bfloat16* __restrict__ A,
                                               const __hip_bfloat16* __restrict__ BT,
                                               void* __restrict__ Cout,
                                               int M, int N, int K) {
  __shared__ __hip_bfloat16 As[128 * 64];
  __shared__ __hip_bfloat16 Bs[128 * 64];
  const int tid = threadIdx.x;
  const int lane = tid & 63, w = tid >> 6;
  const int m0 = blockIdx.y * 128, n0 = blockIdx.x * 128;
  const int wr = (w >> 1) * 64, wc = (w & 1) * 64;
  const int l15 = lane & 15, lg = lane >> 4;

  f32x4 acc[4][4] = {};

  const int srow = lane >> 3;        // row within 8-row chunk (1 KiB)
  const int scol = (lane & 7) * 8;   // bf16 col within row

  for (int k0 = 0; k0 < K; k0 += 64) {
    __syncthreads();
#pragma unroll
    for (int i = 0; i < 4; ++i) {
      const int chunk = i * 4 + w;               // 16 chunks x 1 KiB
      const int row = chunk * 8 + srow;
      __builtin_amdgcn_global_load_lds(AS1(A + (size_t)(m0 + row) * K + k0 + scol),
                                       AS3(As + chunk * 512), 16, 0, 0);
      __builtin_amdgcn_global_load_lds(AS1(BT + (size_t)(n0 + row) * K + k0 + scol),
                                       AS3(Bs + chunk * 512), 16, 0, 0);
    }
    __syncthreads();
#pragma unroll
    for (int kk = 0; kk < 2; ++kk) {
      bf16x8 af[4], bfr[4];
#pragma unroll
      for (int r = 0; r < 4; ++r) {
        af[r]  = *(const bf16x8*)(As + (wr + r * 16 + l15) * 64 + kk * 32 + lg * 8);
        bfr[r] = *(const bf16x8*)(Bs + (wc + r * 16 + l15) * 64 + kk * 32 + lg * 8);
      }
#pragma unroll
      for (int r = 0; r < 4; ++r)
#pragma unroll
        for (int c = 0; c < 4; ++c)
          acc[r][c] = __builtin_amdgcn_mfma_f32_16x16x32_bf16(af[r], bfr[c], acc[r][c], 0, 0, 0);
    }
  }
  // C/D layout: col = lane&15, row = (lane>>4)*4 + i
#pragma unroll
  for (int r = 0; r < 4; ++r)
#pragma unroll
    for (int c = 0; c < 4; ++c)
#pragma unroll
      for (int i = 0; i < 4; ++i) {
        const size_t row = (size_t)(m0 + wr + r * 16 + lg * 4 + i);
        const size_t col = (size_t)(n0 + wc + c * 16 + l15);
        if (OUT_F32)
          ((float*)Cout)[row * N + col] = acc[r][c][i];
        else
          ((__hip_bfloat16*)Cout)[row * N + col] = __float2bfloat16(acc[r][c][i]);
      }
}

// ---------------- flash attention (8-warp 32x32, swapped QK^T, in-reg softmax) ------
// grid: (qtile 8, head 32, batch 2); 512 threads = 8 warps; warp owns 32 q rows.
// Q pre-scaled by (1/sqrt(128))*log2(e) so softmax exp = native v_exp_f32 (2^x).
// LDS: K tile 64x128 (dbuf) + VT tile 128x64 (dbuf) = 64 KB. No P round-trip.
__global__ __launch_bounds__(512) void attn(const __hip_bfloat16* __restrict__ Q,
                                            const __hip_bfloat16* __restrict__ Kp,
                                            const __hip_bfloat16* __restrict__ VT,
                                            __hip_bfloat16* __restrict__ ctx) {
  const int tid = threadIdx.x;
  const int lane = tid & 63, w = tid >> 6;
  const int l31 = lane & 31, hi = lane >> 5;
  const int qt = blockIdx.x, h = blockIdx.y, b = blockIdx.z;
  const int kvh = h >> 2;
  const int q0 = qt * 256 + w * 32;

  const __hip_bfloat16* Qh = Q + (size_t)(b * 2048) * 4096 + h * 128;
  const __hip_bfloat16* Kh = Kp + (size_t)(b * 2048) * 1024 + kvh * 128;
  const __hip_bfloat16* Vh = VT + (size_t)(b * 8 + kvh) * 128 * 2048;

  __shared__ __hip_bfloat16 Ks[2][64 * 128];   // [kv][d], XOR-swizzled 16B units
  __shared__ __hip_bfloat16 Vs[2][128 * 64];   // [d][s],  XOR-swizzled 16B units

  // linear LDS dest (wave-uniform base + lane*16B), inverse-swizzled global source
  auto stage = [&](int buf, int s0) {
#pragma unroll
    for (int j = 0; j < 2; ++j) {
      const int idx = w * 64 + lane + j * 512;       // 16B-unit id
      const int rK = idx >> 4, uK = idx & 15;        // K rows: 16 units of 16B
      __builtin_amdgcn_global_load_lds(
          AS1(Kh + (size_t)(s0 + rK) * 1024 + ((uK ^ (rK & 7)) << 3)),
          AS3(&Ks[buf][(w * 64 + j * 512) * 8]), 16, 0, 0);
      const int rV = idx >> 3, uV = idx & 7;         // VT rows: 8 units of 16B
      __builtin_amdgcn_global_load_lds(
          AS1(Vh + (size_t)rV * 2048 + s0 + ((uV ^ (rV & 7)) << 3)),
          AS3(&Vs[buf][(w * 64 + j * 512) * 8]), 16, 0, 0);
    }
  };

  // Q as B-fragments: B[k=d][col=q]: lane holds Q[q0+l31][kd*16 + hi*8 + j]
  bf16x8 qf[8];
#pragma unroll
  for (int kd = 0; kd < 8; ++kd)
    qf[kd] = *(const bf16x8*)(Qh + (size_t)(q0 + l31) * 4096 + kd * 16 + hi * 8);

  f32x16 o[4] = {};          // O^T[d=32dc+rowmap][q=l31]
  float m = -1e30f, lsum = 0.f;

  stage(0, 0);
  __syncthreads();

  for (int t = 0; t < 32; ++t) {
    const int cur = t & 1;
    if (t < 31) stage(cur ^ 1, (t + 1) * 64);   // prefetch lands under compute

    // S^T[kv][q] = K Q^T : A=K (row=kv), B=Q (col=q)
    f32x16 p[2] = {};
#pragma unroll
    for (int n = 0; n < 2; ++n)
#pragma unroll
      for (int kd = 0; kd < 8; ++kd) {
        const int row = n * 32 + l31;
        bf16x8 kf = *(const bf16x8*)(&Ks[cur][row * 128 + (((2 * kd + hi) ^ (row & 7)) << 3)]);
        p[n] = __builtin_amdgcn_mfma_f32_32x32x16_bf16(kf, qf[kd], p[n], 0, 0, 0);
      }

    // in-register online softmax; q-row = l31 is lane-local (split across hi halves)
    float pmax = p[0][0];
#pragma unroll
    for (int e = 1; e < 16; ++e) pmax = fmaxf(pmax, p[0][e]);
#pragma unroll
    for (int e = 0; e < 16; ++e) pmax = fmaxf(pmax, p[1][e]);
    {
      uint2x r = plswap(__float_as_uint(pmax), __float_as_uint(pmax));
      pmax = fmaxf(__uint_as_float(r[0]), __uint_as_float(r[1]));
    }
    if (!__all(pmax - m <= 8.0f)) {   // defer-max (T13, THR=8 in log2 units)
      const float mnew = fmaxf(m, pmax);
      const float fac = exp2f(m - mnew);
      m = mnew;
      lsum *= fac;
#pragma unroll
      for (int dc = 0; dc < 4; ++dc)
#pragma unroll
        for (int e = 0; e < 16; ++e) o[dc][e] *= fac;
    }
    float rs = 0.f;
#pragma unroll
    for (int n = 0; n < 2; ++n)
#pragma unroll
      for (int e = 0; e < 16; ++e) {
        p[n][e] = exp2f(p[n][e] - m);
        rs += p[n][e];
      }
    {
      uint2x r = plswap(__float_as_uint(rs), __float_as_uint(rs));
      rs = __uint_as_float(r[0]) + __uint_as_float(r[1]);
    }
    lsum += rs;

    // P^T -> B-fragments via cvt_pk + permlane32_swap; O^T += V^T P^T
#pragma unroll
    for (int n = 0; n < 2; ++n)
#pragma unroll
      for (int ks = 0; ks < 2; ++ks) {
        const int bse = ks * 8;
        unsigned a1 = cvtpk_bf16(p[n][bse + 0], p[n][bse + 1]);
        unsigned b1 = cvtpk_bf16(p[n][bse + 4], p[n][bse + 5]);
        unsigned a2 = cvtpk_bf16(p[n][bse + 2], p[n][bse + 3]);
        unsigned b2 = cvtpk_bf16(p[n][bse + 6], p[n][bse + 7]);
        uint2x s1 = plswap(a1, b1);
        uint2x s2 = plswap(a2, b2);
        union { unsigned u[4]; bf16x8 v; } pw = {{s1[0], s2[0], s1[1], s2[1]}};
        const int slot = n * 2 + ks;          // 16-kv contraction slot within KVBLK
#pragma unroll
        for (int dc = 0; dc < 4; ++dc) {
          const int row = dc * 32 + l31;
          bf16x8 vf = *(const bf16x8*)(&Vs[cur][row * 64 + (((2 * slot + hi) ^ (row & 7)) << 3)]);
          o[dc] = __builtin_amdgcn_mfma_f32_32x32x16_bf16(vf, pw.v, o[dc], 0, 0, 0);
        }
      }
    __syncthreads();   // drains prefetch vmcnt; swaps buffers
  }

  // epilogue: O^T[d][q] -> ctx[q][d]; d = dc*32 + 8g + 4hi + e, packed 4-wide
  const float inv = 1.0f / lsum;
  const size_t rowbase = ((size_t)(b * 2048 + q0 + l31)) * 4096 + h * 128;
#pragma unroll
  for (int dc = 0; dc < 4; ++dc)
#pragma unroll
    for (int g = 0; g < 4; ++g) {
      union { unsigned short us[4]; ushort4 u4; } pk;
#pragma unroll
      for (int e = 0; e < 4; ++e) {
        __hip_bfloat16 hv = __float2bfloat16(o[dc][g * 4 + e] * inv);
        pk.us[e] = *(unsigned short*)&hv;
      }
      *(ushort4*)(ctx + rowbase + dc * 32 + g * 8 + hi * 4) = pk.u4;
    }
}

// ---------------- launcher ----------------

extern "C" void kernel_launch(void* const* d_in, const int* in_sizes, int n_in,
                              void* d_out, int out_size, void* d_ws, size_t ws_size,
                              hipStream_t stream) {
  const float* q_in = (const float*)d_in[0];
  const float* k_in = (const float*)d_in[1];
  const float* v_in = (const float*)d_in[2];
  const int* pos    = (const int*)d_in[3];
  const float* Wq   = (const float*)d_in[4];
  const float* Wk   = (const float*)d_in[5];
  const float* Wv   = (const float*)d_in[6];
  const float* Wo   = (const float*)d_in[7];

  char* ws = (char*)d_ws;
  __hip_bfloat16* xbuf = (__hip_bfloat16*)(ws);              // 33.5 MB, reused as ctx
  __hip_bfloat16* WqT  = (__hip_bfloat16*)(ws + 33554432);   // 33.5 MB
  __hip_bfloat16* WkT  = (__hip_bfloat16*)(ws + 67108864);   // 8.4 MB
  __hip_bfloat16* WvT  = (__hip_bfloat16*)(ws + 75497472);   // 8.4 MB
  __hip_bfloat16* WoT  = (__hip_bfloat16*)(ws + 83886080);   // 33.5 MB
  __hip_bfloat16* Qp   = (__hip_bfloat16*)(ws + 117440512);  // 33.5 MB
  __hip_bfloat16* Kp   = (__hip_bfloat16*)(ws + 150994944);  // 8.4 MB
  __hip_bfloat16* Vp   = (__hip_bfloat16*)(ws + 159383552);  // 8.4 MB
  __hip_bfloat16* VTb  = (__hip_bfloat16*)(ws + 167772160);  // 8.4 MB

  const dim3 tb(32, 8);
  wtrans<<<dim3(128, 128), tb, 0, stream>>>(Wq, WqT, 4096, 4096);
  wtrans<<<dim3(32, 128),  tb, 0, stream>>>(Wk, WkT, 4096, 1024);
  wtrans<<<dim3(32, 128),  tb, 0, stream>>>(Wv, WvT, 4096, 1024);
  wtrans<<<dim3(128, 128), tb, 0, stream>>>(Wo, WoT, 4096, 4096);

  // Q path (scale = 1/sqrt(128) * log2(e) so attn can use native exp2)
  xconv<<<16384, 256, 0, stream>>>(q_in, xbuf);
  gemm_bt<0><<<dim3(32, 32), 256, 0, stream>>>(xbuf, WqT, Qp, 4096, 4096, 4096);
  rope<<<32768, 256, 0, stream>>>(Qp, pos, 5, 0.08838834764831845f * 1.4426950408889634f);
  // K path
  xconv<<<16384, 256, 0, stream>>>(k_in, xbuf);
  gemm_bt<0><<<dim3(8, 32), 256, 0, stream>>>(xbuf, WkT, Kp, 4096, 1024, 4096);
  rope<<<8192, 256, 0, stream>>>(Kp, pos, 3, 1.0f);
  // V path
  xconv<<<16384, 256, 0, stream>>>(v_in, xbuf);
  gemm_bt<0><<<dim3(8, 32), 256, 0, stream>>>(xbuf, WvT, Vp, 4096, 1024, 4096);
  vtrans<<<dim3(64, 4, 16), tb, 0, stream>>>(Vp, VTb);

  // attention -> ctx (reuses xbuf)
  attn<<<dim3(8, 32, 2), 512, 0, stream>>>(Qp, Kp, VTb, xbuf);

  // output projection, f32 epilogue straight to d_out
  gemm_bt<1><<<dim3(32, 32), 256, 0, stream>>>(xbuf, WoT, d_out, 4096, 4096, 4096);
}

// Round 5
// 796.211 us; speedup vs baseline: 1.9626x; 1.1945x over previous
//
#include <hip/hip_runtime.h>
#include <hip/hip_bf16.h>

typedef __attribute__((ext_vector_type(8))) short bf16x8;
typedef __attribute__((ext_vector_type(4))) float f32x4;
typedef __attribute__((ext_vector_type(16))) float f32x16;
typedef __attribute__((ext_vector_type(2))) unsigned uint2x;

#define AS1(p) ((const __attribute__((address_space(1))) void*)(p))
#define AS3(p) ((__attribute__((address_space(3))) void*)(p))

__device__ inline unsigned cvtpk_bf16(float lo, float hi) {
  unsigned r;
  asm("v_cvt_pk_bf16_f32 %0, %1, %2" : "=v"(r) : "v"(lo), "v"(hi));
  return r;
}

__device__ inline uint2x plswap(unsigned a, unsigned b) {
  return __builtin_amdgcn_permlane32_swap(a, b, false, false);
}

// ---------------- conversion / transpose kernels ----------------

__global__ __launch_bounds__(256) void xconv(const float* __restrict__ in,
                                             __hip_bfloat16* __restrict__ out) {
  size_t i = ((size_t)blockIdx.x * 256 + threadIdx.x) * 4;
  float4 v = *(const float4*)(in + i);
  union { __hip_bfloat16 h[4]; ushort4 u; } o;
  o.h[0] = __float2bfloat16(v.x);
  o.h[1] = __float2bfloat16(v.y);
  o.h[2] = __float2bfloat16(v.z);
  o.h[3] = __float2bfloat16(v.w);
  *(ushort4*)(out + i) = o.u;
}

// W [K][N] f32  ->  WT [N][K] bf16
__global__ __launch_bounds__(256) void wtrans(const float* __restrict__ W,
                                              __hip_bfloat16* __restrict__ WT,
                                              int K, int N) {
  __shared__ float t[32][33];
  const int n0 = blockIdx.x << 5, k0 = blockIdx.y << 5;
  const int tx = threadIdx.x, ty = threadIdx.y;
#pragma unroll
  for (int j = 0; j < 4; ++j)
    t[ty + j * 8][tx] = W[(size_t)(k0 + ty + j * 8) * N + n0 + tx];
  __syncthreads();
#pragma unroll
  for (int j = 0; j < 4; ++j)
    WT[(size_t)(n0 + ty + j * 8) * K + k0 + tx] = __float2bfloat16(t[tx][ty + j * 8]);
}

// Vp [B*S][1024] bf16 -> VT [B][8][128][2048] bf16
__global__ __launch_bounds__(256) void vtrans(const __hip_bfloat16* __restrict__ V,
                                              __hip_bfloat16* __restrict__ VT) {
  __shared__ float t[32][33];
  const int s0 = blockIdx.x << 5, d0 = blockIdx.y << 5;
  const int b = blockIdx.z >> 3, g = blockIdx.z & 7;
  const int tx = threadIdx.x, ty = threadIdx.y;
#pragma unroll
  for (int j = 0; j < 4; ++j)
    t[ty + j * 8][tx] = __bfloat162float(
        V[(size_t)(b * 2048 + s0 + ty + j * 8) * 1024 + g * 128 + d0 + tx]);
  __syncthreads();
#pragma unroll
  for (int j = 0; j < 4; ++j)
    VT[((size_t)(b * 8 + g) * 128 + d0 + ty + j * 8) * 2048 + s0 + tx] =
        __float2bfloat16(t[tx][ty + j * 8]);
}

// RoPE in place on X [4096 rows][H*128], H = 1<<hbits. scale folded.
__global__ __launch_bounds__(256) void rope(__hip_bfloat16* __restrict__ X,
                                            const int* __restrict__ pos,
                                            int hbits, float scale) {
  const int t = blockIdx.x * 256 + threadIdx.x;
  const int j = t & 63;
  const int rest = t >> 6;
  const int h = rest & ((1 << hbits) - 1);
  const int row = rest >> hbits;
  const float p = (float)pos[row];
  const float fr = p * exp2f((float)j * -0.2076205059304601f); // 10000^(-j/64)
  float sn, cs;
  __sincosf(fr, &sn, &cs);
  const size_t base = (((size_t)row << hbits) + h) * 128 + j;
  const float x0 = __bfloat162float(X[base]);
  const float x1 = __bfloat162float(X[base + 64]);
  X[base]      = __float2bfloat16((x0 * cs - x1 * sn) * scale);
  X[base + 64] = __float2bfloat16((x1 * cs + x0 * sn) * scale);
}

// ---------------- GEMM 128^2 (m97 structure) for N=1024 projections ----------------

template <int OUT_F32>
__global__ __launch_bounds__(256) void gemm_bt(const __hip_bfloat16* __restrict__ A,
                                               const __hip_bfloat16* __restrict__ BT,
                                               void* __restrict__ Cout,
                                               int M, int N, int K) {
  __shared__ __hip_bfloat16 As[128 * 64];
  __shared__ __hip_bfloat16 Bs[128 * 64];
  const int tid = threadIdx.x;
  const int lane = tid & 63, w = tid >> 6;
  const int m0 = blockIdx.y * 128, n0 = blockIdx.x * 128;
  const int wr = (w >> 1) * 64, wc = (w & 1) * 64;
  const int l15 = lane & 15, lg = lane >> 4;

  f32x4 acc[4][4] = {};

  const int srow = lane >> 3;
  const int scol = (lane & 7) * 8;

  for (int k0 = 0; k0 < K; k0 += 64) {
    __syncthreads();
#pragma unroll
    for (int i = 0; i < 4; ++i) {
      const int chunk = i * 4 + w;
      const int row = chunk * 8 + srow;
      __builtin_amdgcn_global_load_lds(AS1(A + (size_t)(m0 + row) * K + k0 + scol),
                                       AS3(As + chunk * 512), 16, 0, 0);
      __builtin_amdgcn_global_load_lds(AS1(BT + (size_t)(n0 + row) * K + k0 + scol),
                                       AS3(Bs + chunk * 512), 16, 0, 0);
    }
    __syncthreads();
#pragma unroll
    for (int kk = 0; kk < 2; ++kk) {
      bf16x8 af[4], bfr[4];
#pragma unroll
      for (int r = 0; r < 4; ++r) {
        af[r]  = *(const bf16x8*)(As + (wr + r * 16 + l15) * 64 + kk * 32 + lg * 8);
        bfr[r] = *(const bf16x8*)(Bs + (wc + r * 16 + l15) * 64 + kk * 32 + lg * 8);
      }
#pragma unroll
      for (int r = 0; r < 4; ++r)
#pragma unroll
        for (int c = 0; c < 4; ++c)
          acc[r][c] = __builtin_amdgcn_mfma_f32_16x16x32_bf16(af[r], bfr[c], acc[r][c], 0, 0, 0);
    }
  }
#pragma unroll
  for (int r = 0; r < 4; ++r)
#pragma unroll
    for (int c = 0; c < 4; ++c)
#pragma unroll
      for (int i = 0; i < 4; ++i) {
        const size_t row = (size_t)(m0 + wr + r * 16 + lg * 4 + i);
        const size_t col = (size_t)(n0 + wc + c * 16 + l15);
        if (OUT_F32)
          ((float*)Cout)[row * N + col] = acc[r][c][i];
        else
          ((__hip_bfloat16*)Cout)[row * N + col] = __float2bfloat16(acc[r][c][i]);
      }
}

// ---------------- GEMM 256^2 8-phase (T2+T3+T4+T5) for 4096-wide projections --------
// BM=BN=256, BK=64, 512 thr = 8 waves (2M x 4N). LDS 128KB = 2buf x (A 32KB + B 32KB).
// LDS tile layout: 1KB subtiles of 16 rows x 32 k; within a subtile, rows 8-15 swap
// 16-elem k-granules (XOR) -> ds_read_b128 column reads are ~4-way instead of 16-way.
// element offset within a 16Kelem tile for logical (row, k):
__device__ inline int tile_off(int row, int k) {
  return (((row >> 4) << 1) + (k >> 5)) * 512 + (row & 15) * 32 +
         ((k & 31) ^ ((row & 8) << 1));
}

// stage half h of A-tile (h=0: 64-row groups {0,2}; h=1: {1,3}) for K-tile at kt.
// Linear LDS dest (1KB/wave-instr = one subtile), inverse-swizzled global source.
__device__ inline void stageA(const __hip_bfloat16* __restrict__ src, int ld, int row0,
                              int kt, int h, __hip_bfloat16* ldsT, int w, int lane) {
#pragma unroll
  for (int li = 0; li < 2; ++li) {
    const int t = li * 8 + w;                      // 16 subtiles
    const int grp = ((t >> 3) << 1) + h;           // 64-row group
    const int srl = (t & 7) >> 1, sk = t & 1;
    const int rowbase = grp * 64 + srl * 16;
    __hip_bfloat16* dst = ldsT + ((((rowbase >> 4) << 1) + sk) << 9);
    const int r = lane >> 2;
    const int ku = (lane & 3) ^ ((r & 8) >> 2);    // inverse swizzle on source
    __builtin_amdgcn_global_load_lds(
        AS1(src + (size_t)(row0 + rowbase + r) * ld + kt + (sk << 5) + (ku << 3)),
        AS3(dst), 16, 0, 0);
  }
}

// stage half h of B-tile (h selects 32-col groups: cols with (col>>5)&1 == h).
__device__ inline void stageB(const __hip_bfloat16* __restrict__ src, int ld, int col0,
                              int kt, int h, __hip_bfloat16* ldsT, int w, int lane) {
#pragma unroll
  for (int li = 0; li < 2; ++li) {
    const int t = li * 8 + w;
    const int q = t >> 2;                          // 64-col quarter
    const int srl = (t >> 1) & 1, sk = t & 1;
    const int colbase = q * 64 + h * 32 + srl * 16;
    __hip_bfloat16* dst = ldsT + ((((colbase >> 4) << 1) + sk) << 9);
    const int r = lane >> 2;
    const int ku = (lane & 3) ^ ((r & 8) >> 2);
    __builtin_amdgcn_global_load_lds(
        AS1(src + (size_t)(col0 + colbase + r) * ld + kt + (sk << 5) + (ku << 3)),
        AS3(dst), 16, 0, 0);
  }
}

template <int OUT_F32>
__global__ __launch_bounds__(512, 1) void gemm256(const __hip_bfloat16* __restrict__ A,
                                                  const __hip_bfloat16* __restrict__ BT,
                                                  void* __restrict__ Cout,
                                                  int M, int N, int K) {
  __shared__ __align__(16) __hip_bfloat16 lds[2][2][16384];
  const int tid = threadIdx.x;
  const int lane = tid & 63, w = tid >> 6;
  const int l15 = lane & 15, lg = lane >> 4;
  const int wm = w >> 2, wn = w & 3;
  // XCD-bijective block swizzle (grid is a multiple of 8)
  const int nbx = N >> 8;
  const int nwg = (M >> 8) * nbx;
  const int bid = blockIdx.x;
  const int swz = (bid & 7) * (nwg >> 3) + (bid >> 3);
  const int m0 = (swz / nbx) << 8, n0 = (swz % nbx) << 8;

  f32x4 acc[8][4] = {};
  const int NT = K >> 6;

  // prologue: tile0 all 4 halves + tile1 {A0,B0}; vmcnt(4) -> tile0 resident
  stageA(A, K, m0, 0, 0, &lds[0][0][0], w, lane);
  stageB(BT, K, n0, 0, 0, &lds[0][1][0], w, lane);
  stageA(A, K, m0, 0, 1, &lds[0][0][0], w, lane);
  stageB(BT, K, n0, 0, 1, &lds[0][1][0], w, lane);
  stageA(A, K, m0, 64, 0, &lds[1][0][0], w, lane);
  stageB(BT, K, n0, 64, 0, &lds[1][1][0], w, lane);
  asm volatile("s_waitcnt vmcnt(4)" ::: "memory");
  __builtin_amdgcn_s_barrier();

  for (int j = 0; j < NT; ++j) {
    const int buf = j & 1;
    const __hip_bfloat16* Ab = &lds[buf][0][0];
    const __hip_bfloat16* Bb = &lds[buf][1][0];
    __hip_bfloat16* An = &lds[buf ^ 1][0][0];
    __hip_bfloat16* Bn = &lds[buf ^ 1][1][0];
    __hip_bfloat16* Ac = &lds[buf][0][0];
    __hip_bfloat16* Bc = &lds[buf][1][0];
    const int kt1 = (j + 1) << 6, kt2 = (j + 2) << 6;
    const bool s1 = (j + 1) < NT, s2 = (j + 2) < NT;

    auto phase = [&](int rq, int cq, int sid) {
      bf16x8 af[2][4], bfr[2][2];
#pragma unroll
      for (int kk = 0; kk < 2; ++kk) {
#pragma unroll
        for (int rf = 0; rf < 4; ++rf)
          af[kk][rf] = *(const bf16x8*)(Ab +
              tile_off(wm * 128 + (rq * 4 + rf) * 16 + l15, kk * 32 + lg * 8));
#pragma unroll
        for (int cf = 0; cf < 2; ++cf)
          bfr[kk][cf] = *(const bf16x8*)(Bb +
              tile_off(wn * 64 + (cq * 2 + cf) * 16 + l15, kk * 32 + lg * 8));
      }
      // stage schedule: ph0: A1*(j+1) ph1: B1*(j+1) ph2: A0*(j+2) ph3: B0*(j+2)
      if (sid == 0)      { if (s1) stageA(A, K, m0, kt1, 1, An, w, lane); }
      else if (sid == 1) { if (s1) stageB(BT, K, n0, kt1, 1, Bn, w, lane); }
      else if (sid == 2) { if (s2) stageA(A, K, m0, kt2, 0, Ac, w, lane); }
      else {
        if (s2) stageB(BT, K, n0, kt2, 0, Bc, w, lane);
        // counted vmcnt ONCE per K-tile: tile j+1 fully resident, last 2 halves in flight
        if (s2) asm volatile("s_waitcnt vmcnt(4)" ::: "memory");
        else    asm volatile("s_waitcnt vmcnt(0)" ::: "memory");
      }
      __builtin_amdgcn_s_barrier();
      asm volatile("s_waitcnt lgkmcnt(0)" ::: "memory");
      __builtin_amdgcn_sched_barrier(0);
      __builtin_amdgcn_s_setprio(1);
#pragma unroll
      for (int kk = 0; kk < 2; ++kk)
#pragma unroll
        for (int rf = 0; rf < 4; ++rf)
#pragma unroll
          for (int cf = 0; cf < 2; ++cf)
            acc[rq * 4 + rf][cq * 2 + cf] = __builtin_amdgcn_mfma_f32_16x16x32_bf16(
                af[kk][rf], bfr[kk][cf], acc[rq * 4 + rf][cq * 2 + cf], 0, 0, 0);
      __builtin_amdgcn_s_setprio(0);
      __builtin_amdgcn_s_barrier();
    };
    phase(0, 0, 0);
    phase(0, 1, 1);
    phase(1, 0, 2);
    phase(1, 1, 3);
  }

  // epilogue: C/D layout col=l15, row=lg*4+i
#pragma unroll
  for (int rf = 0; rf < 8; ++rf)
#pragma unroll
    for (int cf = 0; cf < 4; ++cf)
#pragma unroll
      for (int i = 0; i < 4; ++i) {
        const size_t row = (size_t)(m0 + wm * 128 + rf * 16 + lg * 4 + i);
        const size_t col = (size_t)(n0 + wn * 64 + cf * 16 + l15);
        if (OUT_F32)
          ((float*)Cout)[row * N + col] = acc[rf][cf][i];
        else
          ((__hip_bfloat16*)Cout)[row * N + col] = __float2bfloat16(acc[rf][cf][i]);
      }
}

// ---------------- flash attention (8-warp 32x32, swapped QK^T, in-reg softmax) ------
__global__ __launch_bounds__(512) void attn(const __hip_bfloat16* __restrict__ Q,
                                            const __hip_bfloat16* __restrict__ Kp,
                                            const __hip_bfloat16* __restrict__ VT,
                                            __hip_bfloat16* __restrict__ ctx) {
  const int tid = threadIdx.x;
  const int lane = tid & 63, w = tid >> 6;
  const int l31 = lane & 31, hi = lane >> 5;
  const int qt = blockIdx.x, h = blockIdx.y, b = blockIdx.z;
  const int kvh = h >> 2;
  const int q0 = qt * 256 + w * 32;

  const __hip_bfloat16* Qh = Q + (size_t)(b * 2048) * 4096 + h * 128;
  const __hip_bfloat16* Kh = Kp + (size_t)(b * 2048) * 1024 + kvh * 128;
  const __hip_bfloat16* Vh = VT + (size_t)(b * 8 + kvh) * 128 * 2048;

  __shared__ __hip_bfloat16 Ks[2][64 * 128];
  __shared__ __hip_bfloat16 Vs[2][128 * 64];

  auto stage = [&](int buf, int s0) {
#pragma unroll
    for (int j = 0; j < 2; ++j) {
      const int idx = w * 64 + lane + j * 512;
      const int rK = idx >> 4, uK = idx & 15;
      __builtin_amdgcn_global_load_lds(
          AS1(Kh + (size_t)(s0 + rK) * 1024 + ((uK ^ (rK & 7)) << 3)),
          AS3(&Ks[buf][(w * 64 + j * 512) * 8]), 16, 0, 0);
      const int rV = idx >> 3, uV = idx & 7;
      __builtin_amdgcn_global_load_lds(
          AS1(Vh + (size_t)rV * 2048 + s0 + ((uV ^ (rV & 7)) << 3)),
          AS3(&Vs[buf][(w * 64 + j * 512) * 8]), 16, 0, 0);
    }
  };

  bf16x8 qf[8];
#pragma unroll
  for (int kd = 0; kd < 8; ++kd)
    qf[kd] = *(const bf16x8*)(Qh + (size_t)(q0 + l31) * 4096 + kd * 16 + hi * 8);

  f32x16 o[4] = {};
  float m = -1e30f, lsum = 0.f;

  stage(0, 0);
  __syncthreads();

  for (int t = 0; t < 32; ++t) {
    const int cur = t & 1;
    if (t < 31) stage(cur ^ 1, (t + 1) * 64);

    f32x16 p[2] = {};
#pragma unroll
    for (int n = 0; n < 2; ++n)
#pragma unroll
      for (int kd = 0; kd < 8; ++kd) {
        const int row = n * 32 + l31;
        bf16x8 kf = *(const bf16x8*)(&Ks[cur][row * 128 + (((2 * kd + hi) ^ (row & 7)) << 3)]);
        p[n] = __builtin_amdgcn_mfma_f32_32x32x16_bf16(kf, qf[kd], p[n], 0, 0, 0);
      }

    float pmax = p[0][0];
#pragma unroll
    for (int e = 1; e < 16; ++e) pmax = fmaxf(pmax, p[0][e]);
#pragma unroll
    for (int e = 0; e < 16; ++e) pmax = fmaxf(pmax, p[1][e]);
    {
      uint2x r = plswap(__float_as_uint(pmax), __float_as_uint(pmax));
      pmax = fmaxf(__uint_as_float(r[0]), __uint_as_float(r[1]));
    }
    if (!__all(pmax - m <= 8.0f)) {
      const float mnew = fmaxf(m, pmax);
      const float fac = exp2f(m - mnew);
      m = mnew;
      lsum *= fac;
#pragma unroll
      for (int dc = 0; dc < 4; ++dc)
#pragma unroll
        for (int e = 0; e < 16; ++e) o[dc][e] *= fac;
    }
    float rs = 0.f;
#pragma unroll
    for (int n = 0; n < 2; ++n)
#pragma unroll
      for (int e = 0; e < 16; ++e) {
        p[n][e] = exp2f(p[n][e] - m);
        rs += p[n][e];
      }
    {
      uint2x r = plswap(__float_as_uint(rs), __float_as_uint(rs));
      rs = __uint_as_float(r[0]) + __uint_as_float(r[1]);
    }
    lsum += rs;

#pragma unroll
    for (int n = 0; n < 2; ++n)
#pragma unroll
      for (int ks = 0; ks < 2; ++ks) {
        const int bse = ks * 8;
        unsigned a1 = cvtpk_bf16(p[n][bse + 0], p[n][bse + 1]);
        unsigned b1 = cvtpk_bf16(p[n][bse + 4], p[n][bse + 5]);
        unsigned a2 = cvtpk_bf16(p[n][bse + 2], p[n][bse + 3]);
        unsigned b2 = cvtpk_bf16(p[n][bse + 6], p[n][bse + 7]);
        uint2x s1 = plswap(a1, b1);
        uint2x s2 = plswap(a2, b2);
        union { unsigned u[4]; bf16x8 v; } pw = {{s1[0], s2[0], s1[1], s2[1]}};
        const int slot = n * 2 + ks;
#pragma unroll
        for (int dc = 0; dc < 4; ++dc) {
          const int row = dc * 32 + l31;
          bf16x8 vf = *(const bf16x8*)(&Vs[cur][row * 64 + (((2 * slot + hi) ^ (row & 7)) << 3)]);
          o[dc] = __builtin_amdgcn_mfma_f32_32x32x16_bf16(vf, pw.v, o[dc], 0, 0, 0);
        }
      }
    __syncthreads();
  }

  const float inv = 1.0f / lsum;
  const size_t rowbase = ((size_t)(b * 2048 + q0 + l31)) * 4096 + h * 128;
#pragma unroll
  for (int dc = 0; dc < 4; ++dc)
#pragma unroll
    for (int g = 0; g < 4; ++g) {
      union { unsigned short us[4]; ushort4 u4; } pk;
#pragma unroll
      for (int e = 0; e < 4; ++e) {
        __hip_bfloat16 hv = __float2bfloat16(o[dc][g * 4 + e] * inv);
        pk.us[e] = *(unsigned short*)&hv;
      }
      *(ushort4*)(ctx + rowbase + dc * 32 + g * 8 + hi * 4) = pk.u4;
    }
}

// ---------------- launcher ----------------

extern "C" void kernel_launch(void* const* d_in, const int* in_sizes, int n_in,
                              void* d_out, int out_size, void* d_ws, size_t ws_size,
                              hipStream_t stream) {
  const float* q_in = (const float*)d_in[0];
  const float* k_in = (const float*)d_in[1];
  const float* v_in = (const float*)d_in[2];
  const int* pos    = (const int*)d_in[3];
  const float* Wq   = (const float*)d_in[4];
  const float* Wk   = (const float*)d_in[5];
  const float* Wv   = (const float*)d_in[6];
  const float* Wo   = (const float*)d_in[7];

  char* ws = (char*)d_ws;
  __hip_bfloat16* xbuf = (__hip_bfloat16*)(ws);              // 33.5 MB, reused as ctx
  __hip_bfloat16* WqT  = (__hip_bfloat16*)(ws + 33554432);   // 33.5 MB
  __hip_bfloat16* WkT  = (__hip_bfloat16*)(ws + 67108864);   // 8.4 MB
  __hip_bfloat16* WvT  = (__hip_bfloat16*)(ws + 75497472);   // 8.4 MB
  __hip_bfloat16* WoT  = (__hip_bfloat16*)(ws + 83886080);   // 33.5 MB
  __hip_bfloat16* Qp   = (__hip_bfloat16*)(ws + 117440512);  // 33.5 MB
  __hip_bfloat16* Kp   = (__hip_bfloat16*)(ws + 150994944);  // 8.4 MB
  __hip_bfloat16* Vp   = (__hip_bfloat16*)(ws + 159383552);  // 8.4 MB
  __hip_bfloat16* VTb  = (__hip_bfloat16*)(ws + 167772160);  // 8.4 MB

  const dim3 tb(32, 8);
  wtrans<<<dim3(128, 128), tb, 0, stream>>>(Wq, WqT, 4096, 4096);
  wtrans<<<dim3(32, 128),  tb, 0, stream>>>(Wk, WkT, 4096, 1024);
  wtrans<<<dim3(32, 128),  tb, 0, stream>>>(Wv, WvT, 4096, 1024);
  wtrans<<<dim3(128, 128), tb, 0, stream>>>(Wo, WoT, 4096, 4096);

  // Q path (scale = 1/sqrt(128) * log2(e) so attn can use native exp2)
  xconv<<<16384, 256, 0, stream>>>(q_in, xbuf);
  gemm256<0><<<256, 512, 0, stream>>>(xbuf, WqT, Qp, 4096, 4096, 4096);
  rope<<<32768, 256, 0, stream>>>(Qp, pos, 5, 0.08838834764831845f * 1.4426950408889634f);
  // K path
  xconv<<<16384, 256, 0, stream>>>(k_in, xbuf);
  gemm_bt<0><<<dim3(8, 32), 256, 0, stream>>>(xbuf, WkT, Kp, 4096, 1024, 4096);
  rope<<<8192, 256, 0, stream>>>(Kp, pos, 3, 1.0f);
  // V path
  xconv<<<16384, 256, 0, stream>>>(v_in, xbuf);
  gemm_bt<0><<<dim3(8, 32), 256, 0, stream>>>(xbuf, WvT, Vp, 4096, 1024, 4096);
  vtrans<<<dim3(64, 4, 16), tb, 0, stream>>>(Vp, VTb);

  // attention -> ctx (reuses xbuf)
  attn<<<dim3(8, 32, 2), 512, 0, stream>>>(Qp, Kp, VTb, xbuf);

  // output projection, f32 epilogue straight to d_out
  gemm256<1><<<256, 512, 0, stream>>>(xbuf, WoT, d_out, 4096, 4096, 4096);
}

// Round 6
// 788.205 us; speedup vs baseline: 1.9826x; 1.0102x over previous
//
#include <hip/hip_runtime.h>
#include <hip/hip_bf16.h>

typedef __attribute__((ext_vector_type(8))) short bf16x8;
typedef __attribute__((ext_vector_type(4))) float f32x4;
typedef __attribute__((ext_vector_type(16))) float f32x16;
typedef __attribute__((ext_vector_type(2))) unsigned uint2x;

#define AS1(p) ((const __attribute__((address_space(1))) void*)(p))
#define AS3(p) ((__attribute__((address_space(3))) void*)(p))

__device__ inline unsigned cvtpk_bf16(float lo, float hi) {
  unsigned r;
  asm("v_cvt_pk_bf16_f32 %0, %1, %2" : "=v"(r) : "v"(lo), "v"(hi));
  return r;
}

__device__ inline uint2x plswap(unsigned a, unsigned b) {
  return __builtin_amdgcn_permlane32_swap(a, b, false, false);
}

// ---------------- conversion / transpose kernels ----------------

__global__ __launch_bounds__(256) void xconv(const float* __restrict__ in,
                                             __hip_bfloat16* __restrict__ out) {
  size_t i = ((size_t)blockIdx.x * 256 + threadIdx.x) * 4;
  float4 v = *(const float4*)(in + i);
  union { __hip_bfloat16 h[4]; ushort4 u; } o;
  o.h[0] = __float2bfloat16(v.x);
  o.h[1] = __float2bfloat16(v.y);
  o.h[2] = __float2bfloat16(v.z);
  o.h[3] = __float2bfloat16(v.w);
  *(ushort4*)(out + i) = o.u;
}

// W [K][N] f32  ->  WT [N][K] bf16
__global__ __launch_bounds__(256) void wtrans(const float* __restrict__ W,
                                              __hip_bfloat16* __restrict__ WT,
                                              int K, int N) {
  __shared__ float t[32][33];
  const int n0 = blockIdx.x << 5, k0 = blockIdx.y << 5;
  const int tx = threadIdx.x, ty = threadIdx.y;
#pragma unroll
  for (int j = 0; j < 4; ++j)
    t[ty + j * 8][tx] = W[(size_t)(k0 + ty + j * 8) * N + n0 + tx];
  __syncthreads();
#pragma unroll
  for (int j = 0; j < 4; ++j)
    WT[(size_t)(n0 + ty + j * 8) * K + k0 + tx] = __float2bfloat16(t[tx][ty + j * 8]);
}

// Vp [B*S][1024] bf16 -> VT [B][8][128][2048] bf16
__global__ __launch_bounds__(256) void vtrans(const __hip_bfloat16* __restrict__ V,
                                              __hip_bfloat16* __restrict__ VT) {
  __shared__ float t[32][33];
  const int s0 = blockIdx.x << 5, d0 = blockIdx.y << 5;
  const int b = blockIdx.z >> 3, g = blockIdx.z & 7;
  const int tx = threadIdx.x, ty = threadIdx.y;
#pragma unroll
  for (int j = 0; j < 4; ++j)
    t[ty + j * 8][tx] = __bfloat162float(
        V[(size_t)(b * 2048 + s0 + ty + j * 8) * 1024 + g * 128 + d0 + tx]);
  __syncthreads();
#pragma unroll
  for (int j = 0; j < 4; ++j)
    VT[((size_t)(b * 8 + g) * 128 + d0 + ty + j * 8) * 2048 + s0 + tx] =
        __float2bfloat16(t[tx][ty + j * 8]);
}

// RoPE in place on X [4096 rows][H*128], H = 1<<hbits. scale folded.
__global__ __launch_bounds__(256) void rope(__hip_bfloat16* __restrict__ X,
                                            const int* __restrict__ pos,
                                            int hbits, float scale) {
  const int t = blockIdx.x * 256 + threadIdx.x;
  const int j = t & 63;
  const int rest = t >> 6;
  const int h = rest & ((1 << hbits) - 1);
  const int row = rest >> hbits;
  const float p = (float)pos[row];
  const float fr = p * exp2f((float)j * -0.2076205059304601f); // 10000^(-j/64)
  float sn, cs;
  __sincosf(fr, &sn, &cs);
  const size_t base = (((size_t)row << hbits) + h) * 128 + j;
  const float x0 = __bfloat162float(X[base]);
  const float x1 = __bfloat162float(X[base + 64]);
  X[base]      = __float2bfloat16((x0 * cs - x1 * sn) * scale);
  X[base + 64] = __float2bfloat16((x1 * cs + x0 * sn) * scale);
}

// ---------------- GEMM 128^2 (m97 structure) for N=1024 projections ----------------

template <int OUT_F32>
__global__ __launch_bounds__(256) void gemm_bt(const __hip_bfloat16* __restrict__ A,
                                               const __hip_bfloat16* __restrict__ BT,
                                               void* __restrict__ Cout,
                                               int M, int N, int K) {
  __shared__ __hip_bfloat16 As[128 * 64];
  __shared__ __hip_bfloat16 Bs[128 * 64];
  const int tid = threadIdx.x;
  const int lane = tid & 63, w = tid >> 6;
  const int m0 = blockIdx.y * 128, n0 = blockIdx.x * 128;
  const int wr = (w >> 1) * 64, wc = (w & 1) * 64;
  const int l15 = lane & 15, lg = lane >> 4;

  f32x4 acc[4][4] = {};

  const int srow = lane >> 3;
  const int scol = (lane & 7) * 8;

  for (int k0 = 0; k0 < K; k0 += 64) {
    __syncthreads();
#pragma unroll
    for (int i = 0; i < 4; ++i) {
      const int chunk = i * 4 + w;
      const int row = chunk * 8 + srow;
      __builtin_amdgcn_global_load_lds(AS1(A + (size_t)(m0 + row) * K + k0 + scol),
                                       AS3(As + chunk * 512), 16, 0, 0);
      __builtin_amdgcn_global_load_lds(AS1(BT + (size_t)(n0 + row) * K + k0 + scol),
                                       AS3(Bs + chunk * 512), 16, 0, 0);
    }
    __syncthreads();
#pragma unroll
    for (int kk = 0; kk < 2; ++kk) {
      bf16x8 af[4], bfr[4];
#pragma unroll
      for (int r = 0; r < 4; ++r) {
        af[r]  = *(const bf16x8*)(As + (wr + r * 16 + l15) * 64 + kk * 32 + lg * 8);
        bfr[r] = *(const bf16x8*)(Bs + (wc + r * 16 + l15) * 64 + kk * 32 + lg * 8);
      }
#pragma unroll
      for (int r = 0; r < 4; ++r)
#pragma unroll
        for (int c = 0; c < 4; ++c)
          acc[r][c] = __builtin_amdgcn_mfma_f32_16x16x32_bf16(af[r], bfr[c], acc[r][c], 0, 0, 0);
    }
  }
#pragma unroll
  for (int r = 0; r < 4; ++r)
#pragma unroll
    for (int c = 0; c < 4; ++c)
#pragma unroll
      for (int i = 0; i < 4; ++i) {
        const size_t row = (size_t)(m0 + wr + r * 16 + lg * 4 + i);
        const size_t col = (size_t)(n0 + wc + c * 16 + l15);
        if (OUT_F32)
          ((float*)Cout)[row * N + col] = acc[r][c][i];
        else
          ((__hip_bfloat16*)Cout)[row * N + col] = __float2bfloat16(acc[r][c][i]);
      }
}

// ---------------- GEMM 256^2 8-phase (T2+T3+T4+T5) for 4096-wide projections --------

__device__ inline int tile_off(int row, int k) {
  return (((row >> 4) << 1) + (k >> 5)) * 512 + (row & 15) * 32 +
         ((k & 31) ^ ((row & 8) << 1));
}

__device__ inline void stageA(const __hip_bfloat16* __restrict__ src, int ld, int row0,
                              int kt, int h, __hip_bfloat16* ldsT, int w, int lane) {
#pragma unroll
  for (int li = 0; li < 2; ++li) {
    const int t = li * 8 + w;
    const int grp = ((t >> 3) << 1) + h;
    const int srl = (t & 7) >> 1, sk = t & 1;
    const int rowbase = grp * 64 + srl * 16;
    __hip_bfloat16* dst = ldsT + ((((rowbase >> 4) << 1) + sk) << 9);
    const int r = lane >> 2;
    const int ku = (lane & 3) ^ ((r & 8) >> 2);
    __builtin_amdgcn_global_load_lds(
        AS1(src + (size_t)(row0 + rowbase + r) * ld + kt + (sk << 5) + (ku << 3)),
        AS3(dst), 16, 0, 0);
  }
}

__device__ inline void stageB(const __hip_bfloat16* __restrict__ src, int ld, int col0,
                              int kt, int h, __hip_bfloat16* ldsT, int w, int lane) {
#pragma unroll
  for (int li = 0; li < 2; ++li) {
    const int t = li * 8 + w;
    const int q = t >> 2;
    const int srl = (t >> 1) & 1, sk = t & 1;
    const int colbase = q * 64 + h * 32 + srl * 16;
    __hip_bfloat16* dst = ldsT + ((((colbase >> 4) << 1) + sk) << 9);
    const int r = lane >> 2;
    const int ku = (lane & 3) ^ ((r & 8) >> 2);
    __builtin_amdgcn_global_load_lds(
        AS1(src + (size_t)(col0 + colbase + r) * ld + kt + (sk << 5) + (ku << 3)),
        AS3(dst), 16, 0, 0);
  }
}

template <int OUT_F32>
__global__ __launch_bounds__(512, 1) void gemm256(const __hip_bfloat16* __restrict__ A,
                                                  const __hip_bfloat16* __restrict__ BT,
                                                  void* __restrict__ Cout,
                                                  int M, int N, int K) {
  __shared__ __align__(16) __hip_bfloat16 lds[2][2][16384];
  const int tid = threadIdx.x;
  const int lane = tid & 63, w = tid >> 6;
  const int l15 = lane & 15, lg = lane >> 4;
  const int wm = w >> 2, wn = w & 3;
  const int nbx = N >> 8;
  const int nwg = (M >> 8) * nbx;
  const int bid = blockIdx.x;
  const int swz = (bid & 7) * (nwg >> 3) + (bid >> 3);
  const int m0 = (swz / nbx) << 8, n0 = (swz % nbx) << 8;

  f32x4 acc[8][4] = {};
  const int NT = K >> 6;

  stageA(A, K, m0, 0, 0, &lds[0][0][0], w, lane);
  stageB(BT, K, n0, 0, 0, &lds[0][1][0], w, lane);
  stageA(A, K, m0, 0, 1, &lds[0][0][0], w, lane);
  stageB(BT, K, n0, 0, 1, &lds[0][1][0], w, lane);
  stageA(A, K, m0, 64, 0, &lds[1][0][0], w, lane);
  stageB(BT, K, n0, 64, 0, &lds[1][1][0], w, lane);
  asm volatile("s_waitcnt vmcnt(4)" ::: "memory");
  __builtin_amdgcn_s_barrier();

  for (int j = 0; j < NT; ++j) {
    const int buf = j & 1;
    const __hip_bfloat16* Ab = &lds[buf][0][0];
    const __hip_bfloat16* Bb = &lds[buf][1][0];
    __hip_bfloat16* An = &lds[buf ^ 1][0][0];
    __hip_bfloat16* Bn = &lds[buf ^ 1][1][0];
    __hip_bfloat16* Ac = &lds[buf][0][0];
    __hip_bfloat16* Bc = &lds[buf][1][0];
    const int kt1 = (j + 1) << 6, kt2 = (j + 2) << 6;
    const bool s1 = (j + 1) < NT, s2 = (j + 2) < NT;

    auto phase = [&](int rq, int cq, int sid) {
      bf16x8 af[2][4], bfr[2][2];
#pragma unroll
      for (int kk = 0; kk < 2; ++kk) {
#pragma unroll
        for (int rf = 0; rf < 4; ++rf)
          af[kk][rf] = *(const bf16x8*)(Ab +
              tile_off(wm * 128 + (rq * 4 + rf) * 16 + l15, kk * 32 + lg * 8));
#pragma unroll
        for (int cf = 0; cf < 2; ++cf)
          bfr[kk][cf] = *(const bf16x8*)(Bb +
              tile_off(wn * 64 + (cq * 2 + cf) * 16 + l15, kk * 32 + lg * 8));
      }
      if (sid == 0)      { if (s1) stageA(A, K, m0, kt1, 1, An, w, lane); }
      else if (sid == 1) { if (s1) stageB(BT, K, n0, kt1, 1, Bn, w, lane); }
      else if (sid == 2) { if (s2) stageA(A, K, m0, kt2, 0, Ac, w, lane); }
      else {
        if (s2) stageB(BT, K, n0, kt2, 0, Bc, w, lane);
        if (s2) asm volatile("s_waitcnt vmcnt(4)" ::: "memory");
        else    asm volatile("s_waitcnt vmcnt(0)" ::: "memory");
      }
      __builtin_amdgcn_s_barrier();
      asm volatile("s_waitcnt lgkmcnt(0)" ::: "memory");
      __builtin_amdgcn_sched_barrier(0);
      __builtin_amdgcn_s_setprio(1);
#pragma unroll
      for (int kk = 0; kk < 2; ++kk)
#pragma unroll
        for (int rf = 0; rf < 4; ++rf)
#pragma unroll
          for (int cf = 0; cf < 2; ++cf)
            acc[rq * 4 + rf][cq * 2 + cf] = __builtin_amdgcn_mfma_f32_16x16x32_bf16(
                af[kk][rf], bfr[kk][cf], acc[rq * 4 + rf][cq * 2 + cf], 0, 0, 0);
      __builtin_amdgcn_s_setprio(0);
      __builtin_amdgcn_s_barrier();
    };
    phase(0, 0, 0);
    phase(0, 1, 1);
    phase(1, 0, 2);
    phase(1, 1, 3);
  }

#pragma unroll
  for (int rf = 0; rf < 8; ++rf)
#pragma unroll
    for (int cf = 0; cf < 4; ++cf)
#pragma unroll
      for (int i = 0; i < 4; ++i) {
        const size_t row = (size_t)(m0 + wm * 128 + rf * 16 + lg * 4 + i);
        const size_t col = (size_t)(n0 + wn * 64 + cf * 16 + l15);
        if (OUT_F32)
          ((float*)Cout)[row * N + col] = acc[rf][cf][i];
        else
          ((__hip_bfloat16*)Cout)[row * N + col] = __float2bfloat16(acc[rf][cf][i]);
      }
}

// ---------------- flash attention (8-warp 32x32, swapped QK^T, in-reg softmax) ------
// Unrolled x2 (static LDS buffer index), tree reductions, setprio around MFMA.
__global__ __launch_bounds__(512) void attn(const __hip_bfloat16* __restrict__ Q,
                                            const __hip_bfloat16* __restrict__ Kp,
                                            const __hip_bfloat16* __restrict__ VT,
                                            __hip_bfloat16* __restrict__ ctx) {
  const int tid = threadIdx.x;
  const int lane = tid & 63, w = tid >> 6;
  const int l31 = lane & 31, hi = lane >> 5;
  const int qt = blockIdx.x, h = blockIdx.y, b = blockIdx.z;
  const int kvh = h >> 2;
  const int q0 = qt * 256 + w * 32;

  const __hip_bfloat16* Qh = Q + (size_t)(b * 2048) * 4096 + h * 128;
  const __hip_bfloat16* Kh = Kp + (size_t)(b * 2048) * 1024 + kvh * 128;
  const __hip_bfloat16* Vh = VT + (size_t)(b * 8 + kvh) * 128 * 2048;

  __shared__ __hip_bfloat16 Ks[2][64 * 128];
  __shared__ __hip_bfloat16 Vs[2][128 * 64];

  auto stage = [&](int buf, int s0) {
#pragma unroll
    for (int j = 0; j < 2; ++j) {
      const int idx = w * 64 + lane + j * 512;
      const int rK = idx >> 4, uK = idx & 15;
      __builtin_amdgcn_global_load_lds(
          AS1(Kh + (size_t)(s0 + rK) * 1024 + ((uK ^ (rK & 7)) << 3)),
          AS3(&Ks[buf][(w * 64 + j * 512) * 8]), 16, 0, 0);
      const int rV = idx >> 3, uV = idx & 7;
      __builtin_amdgcn_global_load_lds(
          AS1(Vh + (size_t)rV * 2048 + s0 + ((uV ^ (rV & 7)) << 3)),
          AS3(&Vs[buf][(w * 64 + j * 512) * 8]), 16, 0, 0);
    }
  };

  bf16x8 qf[8];
#pragma unroll
  for (int kd = 0; kd < 8; ++kd)
    qf[kd] = *(const bf16x8*)(Qh + (size_t)(q0 + l31) * 4096 + kd * 16 + hi * 8);

  f32x16 o[4] = {};
  float m = -1e30f, lsum = 0.f;

  stage(0, 0);
  __syncthreads();

  auto tile = [&](int tt, int cur, bool pf) {
    if (pf) stage(cur ^ 1, (tt + 1) * 64);

    // S^T[kv][q] = K Q^T
    f32x16 p[2] = {};
    __builtin_amdgcn_s_setprio(1);
#pragma unroll
    for (int n = 0; n < 2; ++n)
#pragma unroll
      for (int kd = 0; kd < 8; ++kd) {
        const int row = n * 32 + l31;
        bf16x8 kf = *(const bf16x8*)(&Ks[cur][row * 128 + (((2 * kd + hi) ^ (row & 7)) << 3)]);
        p[n] = __builtin_amdgcn_mfma_f32_32x32x16_bf16(kf, qf[kd], p[n], 0, 0, 0);
      }
    __builtin_amdgcn_s_setprio(0);

    // tree max (depth 5; max is exactly associative)
    float t16[16], t8[8], t4[4];
#pragma unroll
    for (int e = 0; e < 16; ++e) t16[e] = fmaxf(p[0][e], p[1][e]);
#pragma unroll
    for (int e = 0; e < 8; ++e) t8[e] = fmaxf(t16[e], t16[e + 8]);
#pragma unroll
    for (int e = 0; e < 4; ++e) t4[e] = fmaxf(t8[e], t8[e + 4]);
    float pmax = fmaxf(fmaxf(t4[0], t4[1]), fmaxf(t4[2], t4[3]));
    {
      uint2x r = plswap(__float_as_uint(pmax), __float_as_uint(pmax));
      pmax = fmaxf(__uint_as_float(r[0]), __uint_as_float(r[1]));
    }
    if (!__all(pmax - m <= 8.0f)) {   // defer-max (T13)
      const float mnew = fmaxf(m, pmax);
      const float fac = exp2f(m - mnew);
      m = mnew;
      lsum *= fac;
#pragma unroll
      for (int dc = 0; dc < 4; ++dc)
#pragma unroll
        for (int e = 0; e < 16; ++e) o[dc][e] *= fac;
    }
#pragma unroll
    for (int n = 0; n < 2; ++n)
#pragma unroll
      for (int e = 0; e < 16; ++e) p[n][e] = exp2f(p[n][e] - m);
    // tree sum (depth 5)
    float s16[16];
#pragma unroll
    for (int e = 0; e < 16; ++e) s16[e] = p[0][e] + p[1][e];
#pragma unroll
    for (int e = 0; e < 8; ++e) s16[e] = s16[e] + s16[e + 8];
#pragma unroll
    for (int e = 0; e < 4; ++e) s16[e] = s16[e] + s16[e + 4];
    float rs = (s16[0] + s16[1]) + (s16[2] + s16[3]);
    {
      uint2x r = plswap(__float_as_uint(rs), __float_as_uint(rs));
      rs = __uint_as_float(r[0]) + __uint_as_float(r[1]);
    }
    lsum += rs;

    // P^T -> B-fragments via cvt_pk + permlane32_swap; O^T += V^T P^T
    __builtin_amdgcn_s_setprio(1);
#pragma unroll
    for (int n = 0; n < 2; ++n)
#pragma unroll
      for (int ks = 0; ks < 2; ++ks) {
        const int bse = ks * 8;
        unsigned a1 = cvtpk_bf16(p[n][bse + 0], p[n][bse + 1]);
        unsigned b1 = cvtpk_bf16(p[n][bse + 4], p[n][bse + 5]);
        unsigned a2 = cvtpk_bf16(p[n][bse + 2], p[n][bse + 3]);
        unsigned b2 = cvtpk_bf16(p[n][bse + 6], p[n][bse + 7]);
        uint2x s1 = plswap(a1, b1);
        uint2x s2 = plswap(a2, b2);
        union { unsigned u[4]; bf16x8 v; } pw = {{s1[0], s2[0], s1[1], s2[1]}};
        const int slot = n * 2 + ks;
#pragma unroll
        for (int dc = 0; dc < 4; ++dc) {
          const int row = dc * 32 + l31;
          bf16x8 vf = *(const bf16x8*)(&Vs[cur][row * 64 + (((2 * slot + hi) ^ (row & 7)) << 3)]);
          o[dc] = __builtin_amdgcn_mfma_f32_32x32x16_bf16(vf, pw.v, o[dc], 0, 0, 0);
        }
      }
    __builtin_amdgcn_s_setprio(0);
    __syncthreads();
  };

  for (int t2 = 0; t2 < 16; ++t2) {
    tile(2 * t2, 0, true);
    tile(2 * t2 + 1, 1, t2 < 15);
  }

  const float inv = 1.0f / lsum;
  const size_t rowbase = ((size_t)(b * 2048 + q0 + l31)) * 4096 + h * 128;
#pragma unroll
  for (int dc = 0; dc < 4; ++dc)
#pragma unroll
    for (int g = 0; g < 4; ++g) {
      union { unsigned short us[4]; ushort4 u4; } pk;
#pragma unroll
      for (int e = 0; e < 4; ++e) {
        __hip_bfloat16 hv = __float2bfloat16(o[dc][g * 4 + e] * inv);
        pk.us[e] = *(unsigned short*)&hv;
      }
      *(ushort4*)(ctx + rowbase + dc * 32 + g * 8 + hi * 4) = pk.u4;
    }
}

// ---------------- launcher ----------------

extern "C" void kernel_launch(void* const* d_in, const int* in_sizes, int n_in,
                              void* d_out, int out_size, void* d_ws, size_t ws_size,
                              hipStream_t stream) {
  const float* q_in = (const float*)d_in[0];
  const float* k_in = (const float*)d_in[1];
  const float* v_in = (const float*)d_in[2];
  const int* pos    = (const int*)d_in[3];
  const float* Wq   = (const float*)d_in[4];
  const float* Wk   = (const float*)d_in[5];
  const float* Wv   = (const float*)d_in[6];
  const float* Wo   = (const float*)d_in[7];

  char* ws = (char*)d_ws;
  __hip_bfloat16* xbuf = (__hip_bfloat16*)(ws);              // 33.5 MB, reused as ctx
  __hip_bfloat16* WqT  = (__hip_bfloat16*)(ws + 33554432);   // 33.5 MB
  __hip_bfloat16* WkT  = (__hip_bfloat16*)(ws + 67108864);   // 8.4 MB
  __hip_bfloat16* WvT  = (__hip_bfloat16*)(ws + 75497472);   // 8.4 MB
  __hip_bfloat16* WoT  = (__hip_bfloat16*)(ws + 83886080);   // 33.5 MB
  __hip_bfloat16* Qp   = (__hip_bfloat16*)(ws + 117440512);  // 33.5 MB
  __hip_bfloat16* Kp   = (__hip_bfloat16*)(ws + 150994944);  // 8.4 MB
  __hip_bfloat16* Vp   = (__hip_bfloat16*)(ws + 159383552);  // 8.4 MB
  __hip_bfloat16* VTb  = (__hip_bfloat16*)(ws + 167772160);  // 8.4 MB

  const dim3 tb(32, 8);
  wtrans<<<dim3(128, 128), tb, 0, stream>>>(Wq, WqT, 4096, 4096);
  wtrans<<<dim3(32, 128),  tb, 0, stream>>>(Wk, WkT, 4096, 1024);
  wtrans<<<dim3(32, 128),  tb, 0, stream>>>(Wv, WvT, 4096, 1024);
  wtrans<<<dim3(128, 128), tb, 0, stream>>>(Wo, WoT, 4096, 4096);

  // Q path (scale = 1/sqrt(128) * log2(e) so attn can use native exp2)
  xconv<<<16384, 256, 0, stream>>>(q_in, xbuf);
  gemm256<0><<<256, 512, 0, stream>>>(xbuf, WqT, Qp, 4096, 4096, 4096);
  rope<<<32768, 256, 0, stream>>>(Qp, pos, 5, 0.08838834764831845f * 1.4426950408889634f);
  // K path
  xconv<<<16384, 256, 0, stream>>>(k_in, xbuf);
  gemm_bt<0><<<dim3(8, 32), 256, 0, stream>>>(xbuf, WkT, Kp, 4096, 1024, 4096);
  rope<<<8192, 256, 0, stream>>>(Kp, pos, 3, 1.0f);
  // V path
  xconv<<<16384, 256, 0, stream>>>(v_in, xbuf);
  gemm_bt<0><<<dim3(8, 32), 256, 0, stream>>>(xbuf, WvT, Vp, 4096, 1024, 4096);
  vtrans<<<dim3(64, 4, 16), tb, 0, stream>>>(Vp, VTb);

  // attention -> ctx (reuses xbuf)
  attn<<<dim3(8, 32, 2), 512, 0, stream>>>(Qp, Kp, VTb, xbuf);

  // output projection, f32 epilogue straight to d_out
  gemm256<1><<<256, 512, 0, stream>>>(xbuf, WoT, d_out, 4096, 4096, 4096);
}

// Round 7
// 670.384 us; speedup vs baseline: 2.3310x; 1.1758x over previous
//
#include <hip/hip_runtime.h>
#include <hip/hip_bf16.h>

typedef __attribute__((ext_vector_type(8))) short bf16x8;
typedef __attribute__((ext_vector_type(4))) float f32x4;
typedef __attribute__((ext_vector_type(16))) float f32x16;
typedef __attribute__((ext_vector_type(2))) unsigned uint2x;

#define AS1(p) ((const __attribute__((address_space(1))) void*)(p))
#define AS3(p) ((__attribute__((address_space(3))) void*)(p))

__device__ inline unsigned cvtpk_bf16(float lo, float hi) {
  unsigned r;
  asm("v_cvt_pk_bf16_f32 %0, %1, %2" : "=v"(r) : "v"(lo), "v"(hi));
  return r;
}

__device__ inline uint2x plswap(unsigned a, unsigned b) {
  return __builtin_amdgcn_permlane32_swap(a, b, false, false);
}

// ---------------- fused conversion / transpose kernels ----------------

// z=0: k_in -> kc ; z=1: v_in -> vc
__global__ __launch_bounds__(256) void xconv_kv(const float* __restrict__ k_in,
                                                const float* __restrict__ v_in,
                                                __hip_bfloat16* __restrict__ kc,
                                                __hip_bfloat16* __restrict__ vc) {
  const float* in = blockIdx.y ? v_in : k_in;
  __hip_bfloat16* out = blockIdx.y ? vc : kc;
  size_t i = ((size_t)blockIdx.x * 256 + threadIdx.x) * 4;
  float4 v = *(const float4*)(in + i);
  union { __hip_bfloat16 h[4]; ushort4 u; } o;
  o.h[0] = __float2bfloat16(v.x);
  o.h[1] = __float2bfloat16(v.y);
  o.h[2] = __float2bfloat16(v.z);
  o.h[3] = __float2bfloat16(v.w);
  *(ushort4*)(out + i) = o.u;
}

__global__ __launch_bounds__(256) void xconv(const float* __restrict__ in,
                                             __hip_bfloat16* __restrict__ out) {
  size_t i = ((size_t)blockIdx.x * 256 + threadIdx.x) * 4;
  float4 v = *(const float4*)(in + i);
  union { __hip_bfloat16 h[4]; ushort4 u; } o;
  o.h[0] = __float2bfloat16(v.x);
  o.h[1] = __float2bfloat16(v.y);
  o.h[2] = __float2bfloat16(v.z);
  o.h[3] = __float2bfloat16(v.w);
  *(ushort4*)(out + i) = o.u;
}

// All 4 weights in one launch. W [K=4096][N] f32 -> WT [N][K] bf16.
// z: 0=Wq(N=4096) 1=Wo(4096) 2=Wk(1024) 3=Wv(1024). Excess x-blocks exit.
__global__ __launch_bounds__(256) void wtransAll(const float* __restrict__ Wq,
                                                 const float* __restrict__ Wo,
                                                 const float* __restrict__ Wk,
                                                 const float* __restrict__ Wv,
                                                 __hip_bfloat16* __restrict__ WqT,
                                                 __hip_bfloat16* __restrict__ WoT,
                                                 __hip_bfloat16* __restrict__ WkT,
                                                 __hip_bfloat16* __restrict__ WvT) {
  const int z = blockIdx.z;
  const int N = (z < 2) ? 4096 : 1024;
  const int n0 = blockIdx.x << 5;
  if (n0 >= N) return;
  const float* W = (z == 0) ? Wq : (z == 1) ? Wo : (z == 2) ? Wk : Wv;
  __hip_bfloat16* WT = (z == 0) ? WqT : (z == 1) ? WoT : (z == 2) ? WkT : WvT;
  __shared__ float t[32][33];
  const int k0 = blockIdx.y << 5;
  const int tx = threadIdx.x, ty = threadIdx.y;
#pragma unroll
  for (int j = 0; j < 4; ++j)
    t[ty + j * 8][tx] = W[(size_t)(k0 + ty + j * 8) * N + n0 + tx];
  __syncthreads();
#pragma unroll
  for (int j = 0; j < 4; ++j)
    WT[(size_t)(n0 + ty + j * 8) * 4096 + k0 + tx] = __float2bfloat16(t[tx][ty + j * 8]);
}

// merged RoPE: blocks [0,32768) -> Qp (hbits=5, scale=qs); [32768,40960) -> Kp (hbits=3, 1.0)
__global__ __launch_bounds__(256) void rope2(__hip_bfloat16* __restrict__ Qp,
                                             __hip_bfloat16* __restrict__ Kp,
                                             const int* __restrict__ pos, float qs) {
  int bid = blockIdx.x;
  __hip_bfloat16* X;
  int hbits; float scale; int t;
  if (bid < 32768) { X = Qp; hbits = 5; scale = qs; t = bid * 256 + threadIdx.x; }
  else { X = Kp; hbits = 3; scale = 1.0f; t = (bid - 32768) * 256 + threadIdx.x; }
  const int j = t & 63;
  const int rest = t >> 6;
  const int h = rest & ((1 << hbits) - 1);
  const int row = rest >> hbits;
  const float p = (float)pos[row];
  const float fr = p * exp2f((float)j * -0.2076205059304601f); // 10000^(-j/64)
  float sn, cs;
  __sincosf(fr, &sn, &cs);
  const size_t base = (((size_t)row << hbits) + h) * 128 + j;
  const float x0 = __bfloat162float(X[base]);
  const float x1 = __bfloat162float(X[base + 64]);
  X[base]      = __float2bfloat16((x0 * cs - x1 * sn) * scale);
  X[base + 64] = __float2bfloat16((x1 * cs + x0 * sn) * scale);
}

// ---------------- fused K+V projection GEMM (m97 128^2 structure, grid.z=2) --------
// z=0: Kp[M][1024] = kc * WkT^T ; z=1: VT[b][g][128][2048] = transpose(vc * WvT^T)
__global__ __launch_bounds__(256) void gemm_kv(const __hip_bfloat16* __restrict__ Ak,
                                               const __hip_bfloat16* __restrict__ Av,
                                               const __hip_bfloat16* __restrict__ BkT,
                                               const __hip_bfloat16* __restrict__ BvT,
                                               __hip_bfloat16* __restrict__ Kp,
                                               __hip_bfloat16* __restrict__ VT) {
  __shared__ __align__(16) __hip_bfloat16 sh[17408];  // As 8192 | Bs 8192 ; T 128x136
  __hip_bfloat16* As = sh;
  __hip_bfloat16* Bs = sh + 8192;
  const int zz = blockIdx.z;
  const __hip_bfloat16* A  = zz ? Av : Ak;
  const __hip_bfloat16* BT = zz ? BvT : BkT;
  const int K = 4096, N = 1024;
  const int tid = threadIdx.x;
  const int lane = tid & 63, w = tid >> 6;
  const int m0 = blockIdx.y * 128, n0 = blockIdx.x * 128;
  const int wr = (w >> 1) * 64, wc = (w & 1) * 64;
  const int l15 = lane & 15, lg = lane >> 4;

  f32x4 acc[4][4] = {};
  const int srow = lane >> 3;
  const int scol = (lane & 7) * 8;

  for (int k0 = 0; k0 < K; k0 += 64) {
    __syncthreads();
#pragma unroll
    for (int i = 0; i < 4; ++i) {
      const int chunk = i * 4 + w;
      const int row = chunk * 8 + srow;
      __builtin_amdgcn_global_load_lds(AS1(A + (size_t)(m0 + row) * K + k0 + scol),
                                       AS3(As + chunk * 512), 16, 0, 0);
      __builtin_amdgcn_global_load_lds(AS1(BT + (size_t)(n0 + row) * K + k0 + scol),
                                       AS3(Bs + chunk * 512), 16, 0, 0);
    }
    __syncthreads();
#pragma unroll
    for (int kk = 0; kk < 2; ++kk) {
      bf16x8 af[4], bfr[4];
#pragma unroll
      for (int r = 0; r < 4; ++r) {
        af[r]  = *(const bf16x8*)(As + (wr + r * 16 + l15) * 64 + kk * 32 + lg * 8);
        bfr[r] = *(const bf16x8*)(Bs + (wc + r * 16 + l15) * 64 + kk * 32 + lg * 8);
      }
#pragma unroll
      for (int r = 0; r < 4; ++r)
#pragma unroll
        for (int c = 0; c < 4; ++c)
          acc[r][c] = __builtin_amdgcn_mfma_f32_16x16x32_bf16(af[r], bfr[c], acc[r][c], 0, 0, 0);
    }
  }

  if (zz == 0) {
    // K path: plain C write (C/D layout: col=l15, row=lg*4+i)
#pragma unroll
    for (int r = 0; r < 4; ++r)
#pragma unroll
      for (int c = 0; c < 4; ++c)
#pragma unroll
        for (int i = 0; i < 4; ++i)
          Kp[(size_t)(m0 + wr + r * 16 + lg * 4 + i) * N + n0 + wc + c * 16 + l15] =
              __float2bfloat16(acc[r][c][i]);
  } else {
    // V path: transpose in LDS, write VT[(b*8+g)*128 + d][s] coalesced along s
    __syncthreads();  // all waves done reading As/Bs
    __hip_bfloat16* T = sh;  // [128][136] bf16 (pad: 272B rows, 16B-aligned)
#pragma unroll
    for (int r = 0; r < 4; ++r)
#pragma unroll
      for (int c = 0; c < 4; ++c) {
        const int col = wc + c * 16 + l15;        // local d
        const int row = wr + r * 16 + lg * 4;     // local s (4 consecutive)
        union { __hip_bfloat16 h[4]; unsigned long long u; } pkv;
#pragma unroll
        for (int i = 0; i < 4; ++i) pkv.h[i] = __float2bfloat16(acc[r][c][i]);
        *(unsigned long long*)(T + col * 136 + row) = pkv.u;
      }
    __syncthreads();
    const int b = m0 >> 11, s0g = m0 & 2047, g = n0 >> 7;
    __hip_bfloat16* Vh = VT + (size_t)(b * 8 + g) * 128 * 2048;
    const int chunk = tid & 15;
#pragma unroll
    for (int it = 0; it < 8; ++it) {
      const int d = it * 16 + (tid >> 4);
      bf16x8 vv = *(const bf16x8*)(T + d * 136 + chunk * 8);
      *(bf16x8*)(Vh + (size_t)d * 2048 + s0g + chunk * 8) = vv;
    }
  }
}

// ---------------- GEMM 256^2 8-phase (T2+T3+T4+T5) for 4096-wide projections --------

__device__ inline int tile_off(int row, int k) {
  return (((row >> 4) << 1) + (k >> 5)) * 512 + (row & 15) * 32 +
         ((k & 31) ^ ((row & 8) << 1));
}

__device__ inline void stageA(const __hip_bfloat16* __restrict__ src, int ld, int row0,
                              int kt, int h, __hip_bfloat16* ldsT, int w, int lane) {
#pragma unroll
  for (int li = 0; li < 2; ++li) {
    const int t = li * 8 + w;
    const int grp = ((t >> 3) << 1) + h;
    const int srl = (t & 7) >> 1, sk = t & 1;
    const int rowbase = grp * 64 + srl * 16;
    __hip_bfloat16* dst = ldsT + ((((rowbase >> 4) << 1) + sk) << 9);
    const int r = lane >> 2;
    const int ku = (lane & 3) ^ ((r & 8) >> 2);
    __builtin_amdgcn_global_load_lds(
        AS1(src + (size_t)(row0 + rowbase + r) * ld + kt + (sk << 5) + (ku << 3)),
        AS3(dst), 16, 0, 0);
  }
}

__device__ inline void stageB(const __hip_bfloat16* __restrict__ src, int ld, int col0,
                              int kt, int h, __hip_bfloat16* ldsT, int w, int lane) {
#pragma unroll
  for (int li = 0; li < 2; ++li) {
    const int t = li * 8 + w;
    const int q = t >> 2;
    const int srl = (t >> 1) & 1, sk = t & 1;
    const int colbase = q * 64 + h * 32 + srl * 16;
    __hip_bfloat16* dst = ldsT + ((((colbase >> 4) << 1) + sk) << 9);
    const int r = lane >> 2;
    const int ku = (lane & 3) ^ ((r & 8) >> 2);
    __builtin_amdgcn_global_load_lds(
        AS1(src + (size_t)(col0 + colbase + r) * ld + kt + (sk << 5) + (ku << 3)),
        AS3(dst), 16, 0, 0);
  }
}

template <int OUT_F32>
__global__ __launch_bounds__(512, 1) void gemm256(const __hip_bfloat16* __restrict__ A,
                                                  const __hip_bfloat16* __restrict__ BT,
                                                  void* __restrict__ Cout,
                                                  int M, int N, int K) {
  __shared__ __align__(16) __hip_bfloat16 lds[2][2][16384];
  const int tid = threadIdx.x;
  const int lane = tid & 63, w = tid >> 6;
  const int l15 = lane & 15, lg = lane >> 4;
  const int wm = w >> 2, wn = w & 3;
  const int nbx = N >> 8;
  const int nwg = (M >> 8) * nbx;
  const int bid = blockIdx.x;
  const int swz = (bid & 7) * (nwg >> 3) + (bid >> 3);
  const int m0 = (swz / nbx) << 8, n0 = (swz % nbx) << 8;

  f32x4 acc[8][4] = {};
  const int NT = K >> 6;

  stageA(A, K, m0, 0, 0, &lds[0][0][0], w, lane);
  stageB(BT, K, n0, 0, 0, &lds[0][1][0], w, lane);
  stageA(A, K, m0, 0, 1, &lds[0][0][0], w, lane);
  stageB(BT, K, n0, 0, 1, &lds[0][1][0], w, lane);
  stageA(A, K, m0, 64, 0, &lds[1][0][0], w, lane);
  stageB(BT, K, n0, 64, 0, &lds[1][1][0], w, lane);
  asm volatile("s_waitcnt vmcnt(4)" ::: "memory");
  __builtin_amdgcn_s_barrier();

  for (int j = 0; j < NT; ++j) {
    const int buf = j & 1;
    const __hip_bfloat16* Ab = &lds[buf][0][0];
    const __hip_bfloat16* Bb = &lds[buf][1][0];
    __hip_bfloat16* An = &lds[buf ^ 1][0][0];
    __hip_bfloat16* Bn = &lds[buf ^ 1][1][0];
    __hip_bfloat16* Ac = &lds[buf][0][0];
    __hip_bfloat16* Bc = &lds[buf][1][0];
    const int kt1 = (j + 1) << 6, kt2 = (j + 2) << 6;
    const bool s1 = (j + 1) < NT, s2 = (j + 2) < NT;

    auto phase = [&](int rq, int cq, int sid) {
      bf16x8 af[2][4], bfr[2][2];
#pragma unroll
      for (int kk = 0; kk < 2; ++kk) {
#pragma unroll
        for (int rf = 0; rf < 4; ++rf)
          af[kk][rf] = *(const bf16x8*)(Ab +
              tile_off(wm * 128 + (rq * 4 + rf) * 16 + l15, kk * 32 + lg * 8));
#pragma unroll
        for (int cf = 0; cf < 2; ++cf)
          bfr[kk][cf] = *(const bf16x8*)(Bb +
              tile_off(wn * 64 + (cq * 2 + cf) * 16 + l15, kk * 32 + lg * 8));
      }
      if (sid == 0)      { if (s1) stageA(A, K, m0, kt1, 1, An, w, lane); }
      else if (sid == 1) { if (s1) stageB(BT, K, n0, kt1, 1, Bn, w, lane); }
      else if (sid == 2) { if (s2) stageA(A, K, m0, kt2, 0, Ac, w, lane); }
      else {
        if (s2) stageB(BT, K, n0, kt2, 0, Bc, w, lane);
        if (s2) asm volatile("s_waitcnt vmcnt(4)" ::: "memory");
        else    asm volatile("s_waitcnt vmcnt(0)" ::: "memory");
      }
      __builtin_amdgcn_s_barrier();
      asm volatile("s_waitcnt lgkmcnt(0)" ::: "memory");
      __builtin_amdgcn_sched_barrier(0);
      __builtin_amdgcn_s_setprio(1);
#pragma unroll
      for (int kk = 0; kk < 2; ++kk)
#pragma unroll
        for (int rf = 0; rf < 4; ++rf)
#pragma unroll
          for (int cf = 0; cf < 2; ++cf)
            acc[rq * 4 + rf][cq * 2 + cf] = __builtin_amdgcn_mfma_f32_16x16x32_bf16(
                af[kk][rf], bfr[kk][cf], acc[rq * 4 + rf][cq * 2 + cf], 0, 0, 0);
      __builtin_amdgcn_s_setprio(0);
      __builtin_amdgcn_s_barrier();
    };
    phase(0, 0, 0);
    phase(0, 1, 1);
    phase(1, 0, 2);
    phase(1, 1, 3);
  }

#pragma unroll
  for (int rf = 0; rf < 8; ++rf)
#pragma unroll
    for (int cf = 0; cf < 4; ++cf)
#pragma unroll
      for (int i = 0; i < 4; ++i) {
        const size_t row = (size_t)(m0 + wm * 128 + rf * 16 + lg * 4 + i);
        const size_t col = (size_t)(n0 + wn * 64 + cf * 16 + l15);
        if (OUT_F32)
          ((float*)Cout)[row * N + col] = acc[rf][cf][i];
        else
          ((__hip_bfloat16*)Cout)[row * N + col] = __float2bfloat16(acc[rf][cf][i]);
      }
}

// ---------------- flash attention (8-warp 32x32, swapped QK^T, in-reg softmax) ------
__global__ __launch_bounds__(512) void attn(const __hip_bfloat16* __restrict__ Q,
                                            const __hip_bfloat16* __restrict__ Kp,
                                            const __hip_bfloat16* __restrict__ VT,
                                            __hip_bfloat16* __restrict__ ctx) {
  const int tid = threadIdx.x;
  const int lane = tid & 63, w = tid >> 6;
  const int l31 = lane & 31, hi = lane >> 5;
  const int qt = blockIdx.x, h = blockIdx.y, b = blockIdx.z;
  const int kvh = h >> 2;
  const int q0 = qt * 256 + w * 32;

  const __hip_bfloat16* Qh = Q + (size_t)(b * 2048) * 4096 + h * 128;
  const __hip_bfloat16* Kh = Kp + (size_t)(b * 2048) * 1024 + kvh * 128;
  const __hip_bfloat16* Vh = VT + (size_t)(b * 8 + kvh) * 128 * 2048;

  __shared__ __hip_bfloat16 Ks[2][64 * 128];
  __shared__ __hip_bfloat16 Vs[2][128 * 64];

  auto stage = [&](int buf, int s0) {
#pragma unroll
    for (int j = 0; j < 2; ++j) {
      const int idx = w * 64 + lane + j * 512;
      const int rK = idx >> 4, uK = idx & 15;
      __builtin_amdgcn_global_load_lds(
          AS1(Kh + (size_t)(s0 + rK) * 1024 + ((uK ^ (rK & 7)) << 3)),
          AS3(&Ks[buf][(w * 64 + j * 512) * 8]), 16, 0, 0);
      const int rV = idx >> 3, uV = idx & 7;
      __builtin_amdgcn_global_load_lds(
          AS1(Vh + (size_t)rV * 2048 + s0 + ((uV ^ (rV & 7)) << 3)),
          AS3(&Vs[buf][(w * 64 + j * 512) * 8]), 16, 0, 0);
    }
  };

  bf16x8 qf[8];
#pragma unroll
  for (int kd = 0; kd < 8; ++kd)
    qf[kd] = *(const bf16x8*)(Qh + (size_t)(q0 + l31) * 4096 + kd * 16 + hi * 8);

  f32x16 o[4] = {};
  float m = -1e30f, lsum = 0.f;

  stage(0, 0);
  __syncthreads();

  auto tile = [&](int tt, int cur, bool pf) {
    if (pf) stage(cur ^ 1, (tt + 1) * 64);

    f32x16 p[2] = {};
    __builtin_amdgcn_s_setprio(1);
#pragma unroll
    for (int n = 0; n < 2; ++n)
#pragma unroll
      for (int kd = 0; kd < 8; ++kd) {
        const int row = n * 32 + l31;
        bf16x8 kf = *(const bf16x8*)(&Ks[cur][row * 128 + (((2 * kd + hi) ^ (row & 7)) << 3)]);
        p[n] = __builtin_amdgcn_mfma_f32_32x32x16_bf16(kf, qf[kd], p[n], 0, 0, 0);
      }
    __builtin_amdgcn_s_setprio(0);

    float t16[16], t8[8], t4[4];
#pragma unroll
    for (int e = 0; e < 16; ++e) t16[e] = fmaxf(p[0][e], p[1][e]);
#pragma unroll
    for (int e = 0; e < 8; ++e) t8[e] = fmaxf(t16[e], t16[e + 8]);
#pragma unroll
    for (int e = 0; e < 4; ++e) t4[e] = fmaxf(t8[e], t8[e + 4]);
    float pmax = fmaxf(fmaxf(t4[0], t4[1]), fmaxf(t4[2], t4[3]));
    {
      uint2x r = plswap(__float_as_uint(pmax), __float_as_uint(pmax));
      pmax = fmaxf(__uint_as_float(r[0]), __uint_as_float(r[1]));
    }
    if (!__all(pmax - m <= 8.0f)) {   // defer-max (T13)
      const float mnew = fmaxf(m, pmax);
      const float fac = exp2f(m - mnew);
      m = mnew;
      lsum *= fac;
#pragma unroll
      for (int dc = 0; dc < 4; ++dc)
#pragma unroll
        for (int e = 0; e < 16; ++e) o[dc][e] *= fac;
    }
#pragma unroll
    for (int n = 0; n < 2; ++n)
#pragma unroll
      for (int e = 0; e < 16; ++e) p[n][e] = exp2f(p[n][e] - m);
    float s16[16];
#pragma unroll
    for (int e = 0; e < 16; ++e) s16[e] = p[0][e] + p[1][e];
#pragma unroll
    for (int e = 0; e < 8; ++e) s16[e] = s16[e] + s16[e + 8];
#pragma unroll
    for (int e = 0; e < 4; ++e) s16[e] = s16[e] + s16[e + 4];
    float rs = (s16[0] + s16[1]) + (s16[2] + s16[3]);
    {
      uint2x r = plswap(__float_as_uint(rs), __float_as_uint(rs));
      rs = __uint_as_float(r[0]) + __uint_as_float(r[1]);
    }
    lsum += rs;

    __builtin_amdgcn_s_setprio(1);
#pragma unroll
    for (int n = 0; n < 2; ++n)
#pragma unroll
      for (int ks = 0; ks < 2; ++ks) {
        const int bse = ks * 8;
        unsigned a1 = cvtpk_bf16(p[n][bse + 0], p[n][bse + 1]);
        unsigned b1 = cvtpk_bf16(p[n][bse + 4], p[n][bse + 5]);
        unsigned a2 = cvtpk_bf16(p[n][bse + 2], p[n][bse + 3]);
        unsigned b2 = cvtpk_bf16(p[n][bse + 6], p[n][bse + 7]);
        uint2x s1 = plswap(a1, b1);
        uint2x s2 = plswap(a2, b2);
        union { unsigned u[4]; bf16x8 v; } pw = {{s1[0], s2[0], s1[1], s2[1]}};
        const int slot = n * 2 + ks;
#pragma unroll
        for (int dc = 0; dc < 4; ++dc) {
          const int row = dc * 32 + l31;
          bf16x8 vf = *(const bf16x8*)(&Vs[cur][row * 64 + (((2 * slot + hi) ^ (row & 7)) << 3)]);
          o[dc] = __builtin_amdgcn_mfma_f32_32x32x16_bf16(vf, pw.v, o[dc], 0, 0, 0);
        }
      }
    __builtin_amdgcn_s_setprio(0);
    __syncthreads();
  };

  for (int t2 = 0; t2 < 16; ++t2) {
    tile(2 * t2, 0, true);
    tile(2 * t2 + 1, 1, t2 < 15);
  }

  const float inv = 1.0f / lsum;
  const size_t rowbase = ((size_t)(b * 2048 + q0 + l31)) * 4096 + h * 128;
#pragma unroll
  for (int dc = 0; dc < 4; ++dc)
#pragma unroll
    for (int g = 0; g < 4; ++g) {
      union { unsigned short us[4]; ushort4 u4; } pk;
#pragma unroll
      for (int e = 0; e < 4; ++e) {
        __hip_bfloat16 hv = __float2bfloat16(o[dc][g * 4 + e] * inv);
        pk.us[e] = *(unsigned short*)&hv;
      }
      *(ushort4*)(ctx + rowbase + dc * 32 + g * 8 + hi * 4) = pk.u4;
    }
}

// ---------------- launcher ----------------

extern "C" void kernel_launch(void* const* d_in, const int* in_sizes, int n_in,
                              void* d_out, int out_size, void* d_ws, size_t ws_size,
                              hipStream_t stream) {
  const float* q_in = (const float*)d_in[0];
  const float* k_in = (const float*)d_in[1];
  const float* v_in = (const float*)d_in[2];
  const int* pos    = (const int*)d_in[3];
  const float* Wq   = (const float*)d_in[4];
  const float* Wk   = (const float*)d_in[5];
  const float* Wv   = (const float*)d_in[6];
  const float* Wo   = (const float*)d_in[7];

  char* ws = (char*)d_ws;
  __hip_bfloat16* xbuf = (__hip_bfloat16*)(ws);              // qconv -> kconv -> ctx
  __hip_bfloat16* WqT  = (__hip_bfloat16*)(ws + 33554432);   // WqT -> vconv
  __hip_bfloat16* WkT  = (__hip_bfloat16*)(ws + 67108864);
  __hip_bfloat16* WvT  = (__hip_bfloat16*)(ws + 75497472);
  __hip_bfloat16* WoT  = (__hip_bfloat16*)(ws + 83886080);
  __hip_bfloat16* Qp   = (__hip_bfloat16*)(ws + 117440512);
  __hip_bfloat16* Kp   = (__hip_bfloat16*)(ws + 150994944);
  __hip_bfloat16* VTb  = (__hip_bfloat16*)(ws + 167772160);
  __hip_bfloat16* vconv = WqT;  // WqT is dead after gemm256-Q

  // 1) all weight transposes (one launch)
  wtransAll<<<dim3(128, 128, 4), dim3(32, 8), 0, stream>>>(Wq, Wo, Wk, Wv,
                                                           WqT, WoT, WkT, WvT);
  // 2) Q path (scale = 1/sqrt(128) * log2(e) folded into rope)
  xconv<<<16384, 256, 0, stream>>>(q_in, xbuf);
  gemm256<0><<<256, 512, 0, stream>>>(xbuf, WqT, Qp, 4096, 4096, 4096);
  // 3) K+V conversions (one launch; kconv over dead qconv, vconv over dead WqT)
  xconv_kv<<<dim3(16384, 2), 256, 0, stream>>>(k_in, v_in, xbuf, vconv);
  // 4) fused K+V projection; V epilogue writes VT directly
  gemm_kv<<<dim3(8, 32, 2), 256, 0, stream>>>(xbuf, vconv, WkT, WvT, Kp, VTb);
  // 5) RoPE on Q and K (one launch)
  rope2<<<40960, 256, 0, stream>>>(Qp, Kp, pos,
                                   0.08838834764831845f * 1.4426950408889634f);
  // 6) attention -> ctx (reuses xbuf; kconv dead)
  attn<<<dim3(8, 32, 2), 512, 0, stream>>>(Qp, Kp, VTb, xbuf);
  // 7) output projection, f32 epilogue straight to d_out
  gemm256<1><<<256, 512, 0, stream>>>(xbuf, WoT, d_out, 4096, 4096, 4096);
}

// Round 8
// 662.364 us; speedup vs baseline: 2.3592x; 1.0121x over previous
//
#include <hip/hip_runtime.h>
#include <hip/hip_bf16.h>

typedef __attribute__((ext_vector_type(8))) short bf16x8;
typedef __attribute__((ext_vector_type(4))) float f32x4;
typedef __attribute__((ext_vector_type(16))) float f32x16;
typedef __attribute__((ext_vector_type(2))) float f32x2;
typedef __attribute__((ext_vector_type(2))) unsigned uint2x;

#define AS1(p) ((const __attribute__((address_space(1))) void*)(p))
#define AS3(p) ((__attribute__((address_space(3))) void*)(p))

__device__ inline unsigned cvtpk_bf16(float lo, float hi) {
  unsigned r;
  asm("v_cvt_pk_bf16_f32 %0, %1, %2" : "=v"(r) : "v"(lo), "v"(hi));
  return r;
}

__device__ inline uint2x plswap(unsigned a, unsigned b) {
  return __builtin_amdgcn_permlane32_swap(a, b, false, false);
}

// VOP3P dual-f32 packed ops (CDNA2+): operate on adjacent aligned VGPR pairs.
__device__ inline f32x2 pkadd(f32x2 a, f32x2 b) {
  f32x2 d;
  asm("v_pk_add_f32 %0, %1, %2" : "=v"(d) : "v"(a), "v"(b));
  return d;
}
__device__ inline f32x2 pkmul(f32x2 a, f32x2 b) {
  f32x2 d;
  asm("v_pk_mul_f32 %0, %1, %2" : "=v"(d) : "v"(a), "v"(b));
  return d;
}

// ---------------- fused conversion / transpose kernels ----------------

__global__ __launch_bounds__(256) void xconv_kv(const float* __restrict__ k_in,
                                                const float* __restrict__ v_in,
                                                __hip_bfloat16* __restrict__ kc,
                                                __hip_bfloat16* __restrict__ vc) {
  const float* in = blockIdx.y ? v_in : k_in;
  __hip_bfloat16* out = blockIdx.y ? vc : kc;
  size_t i = ((size_t)blockIdx.x * 256 + threadIdx.x) * 4;
  float4 v = *(const float4*)(in + i);
  union { __hip_bfloat16 h[4]; ushort4 u; } o;
  o.h[0] = __float2bfloat16(v.x);
  o.h[1] = __float2bfloat16(v.y);
  o.h[2] = __float2bfloat16(v.z);
  o.h[3] = __float2bfloat16(v.w);
  *(ushort4*)(out + i) = o.u;
}

__global__ __launch_bounds__(256) void xconv(const float* __restrict__ in,
                                             __hip_bfloat16* __restrict__ out) {
  size_t i = ((size_t)blockIdx.x * 256 + threadIdx.x) * 4;
  float4 v = *(const float4*)(in + i);
  union { __hip_bfloat16 h[4]; ushort4 u; } o;
  o.h[0] = __float2bfloat16(v.x);
  o.h[1] = __float2bfloat16(v.y);
  o.h[2] = __float2bfloat16(v.z);
  o.h[3] = __float2bfloat16(v.w);
  *(ushort4*)(out + i) = o.u;
}

// All 4 weights in one launch. W [K=4096][N] f32 -> WT [N][K] bf16.
__global__ __launch_bounds__(256) void wtransAll(const float* __restrict__ Wq,
                                                 const float* __restrict__ Wo,
                                                 const float* __restrict__ Wk,
                                                 const float* __restrict__ Wv,
                                                 __hip_bfloat16* __restrict__ WqT,
                                                 __hip_bfloat16* __restrict__ WoT,
                                                 __hip_bfloat16* __restrict__ WkT,
                                                 __hip_bfloat16* __restrict__ WvT) {
  const int z = blockIdx.z;
  const int N = (z < 2) ? 4096 : 1024;
  const int n0 = blockIdx.x << 5;
  if (n0 >= N) return;
  const float* W = (z == 0) ? Wq : (z == 1) ? Wo : (z == 2) ? Wk : Wv;
  __hip_bfloat16* WT = (z == 0) ? WqT : (z == 1) ? WoT : (z == 2) ? WkT : WvT;
  __shared__ float t[32][33];
  const int k0 = blockIdx.y << 5;
  const int tx = threadIdx.x, ty = threadIdx.y;
#pragma unroll
  for (int j = 0; j < 4; ++j)
    t[ty + j * 8][tx] = W[(size_t)(k0 + ty + j * 8) * N + n0 + tx];
  __syncthreads();
#pragma unroll
  for (int j = 0; j < 4; ++j)
    WT[(size_t)(n0 + ty + j * 8) * 4096 + k0 + tx] = __float2bfloat16(t[tx][ty + j * 8]);
}

// RoPE in place on X [4096 rows][H*128], H = 1<<hbits. (K path only now.)
__global__ __launch_bounds__(256) void rope(__hip_bfloat16* __restrict__ X,
                                            const int* __restrict__ pos,
                                            int hbits, float scale) {
  const int t = blockIdx.x * 256 + threadIdx.x;
  const int j = t & 63;
  const int rest = t >> 6;
  const int h = rest & ((1 << hbits) - 1);
  const int row = rest >> hbits;
  const float p = (float)pos[row];
  const float fr = p * exp2f((float)j * -0.2076205059304601f); // 10000^(-j/64)
  float sn, cs;
  __sincosf(fr, &sn, &cs);
  const size_t base = (((size_t)row << hbits) + h) * 128 + j;
  const float x0 = __bfloat162float(X[base]);
  const float x1 = __bfloat162float(X[base + 64]);
  X[base]      = __float2bfloat16((x0 * cs - x1 * sn) * scale);
  X[base + 64] = __float2bfloat16((x1 * cs + x0 * sn) * scale);
}

// ---------------- fused K+V projection GEMM (m97 128^2 structure, grid.z=2) --------
__global__ __launch_bounds__(256) void gemm_kv(const __hip_bfloat16* __restrict__ Ak,
                                               const __hip_bfloat16* __restrict__ Av,
                                               const __hip_bfloat16* __restrict__ BkT,
                                               const __hip_bfloat16* __restrict__ BvT,
                                               __hip_bfloat16* __restrict__ Kp,
                                               __hip_bfloat16* __restrict__ VT) {
  __shared__ __align__(16) __hip_bfloat16 sh[17408];  // As 8192 | Bs 8192 ; T 128x136
  __hip_bfloat16* As = sh;
  __hip_bfloat16* Bs = sh + 8192;
  const int zz = blockIdx.z;
  const __hip_bfloat16* A  = zz ? Av : Ak;
  const __hip_bfloat16* BT = zz ? BvT : BkT;
  const int K = 4096, N = 1024;
  const int tid = threadIdx.x;
  const int lane = tid & 63, w = tid >> 6;
  const int m0 = blockIdx.y * 128, n0 = blockIdx.x * 128;
  const int wr = (w >> 1) * 64, wc = (w & 1) * 64;
  const int l15 = lane & 15, lg = lane >> 4;

  f32x4 acc[4][4] = {};
  const int srow = lane >> 3;
  const int scol = (lane & 7) * 8;

  for (int k0 = 0; k0 < K; k0 += 64) {
    __syncthreads();
#pragma unroll
    for (int i = 0; i < 4; ++i) {
      const int chunk = i * 4 + w;
      const int row = chunk * 8 + srow;
      __builtin_amdgcn_global_load_lds(AS1(A + (size_t)(m0 + row) * K + k0 + scol),
                                       AS3(As + chunk * 512), 16, 0, 0);
      __builtin_amdgcn_global_load_lds(AS1(BT + (size_t)(n0 + row) * K + k0 + scol),
                                       AS3(Bs + chunk * 512), 16, 0, 0);
    }
    __syncthreads();
#pragma unroll
    for (int kk = 0; kk < 2; ++kk) {
      bf16x8 af[4], bfr[4];
#pragma unroll
      for (int r = 0; r < 4; ++r) {
        af[r]  = *(const bf16x8*)(As + (wr + r * 16 + l15) * 64 + kk * 32 + lg * 8);
        bfr[r] = *(const bf16x8*)(Bs + (wc + r * 16 + l15) * 64 + kk * 32 + lg * 8);
      }
#pragma unroll
      for (int r = 0; r < 4; ++r)
#pragma unroll
        for (int c = 0; c < 4; ++c)
          acc[r][c] = __builtin_amdgcn_mfma_f32_16x16x32_bf16(af[r], bfr[c], acc[r][c], 0, 0, 0);
    }
  }

  if (zz == 0) {
#pragma unroll
    for (int r = 0; r < 4; ++r)
#pragma unroll
      for (int c = 0; c < 4; ++c)
#pragma unroll
        for (int i = 0; i < 4; ++i)
          Kp[(size_t)(m0 + wr + r * 16 + lg * 4 + i) * N + n0 + wc + c * 16 + l15] =
              __float2bfloat16(acc[r][c][i]);
  } else {
    __syncthreads();
    __hip_bfloat16* T = sh;  // [128][136]
#pragma unroll
    for (int r = 0; r < 4; ++r)
#pragma unroll
      for (int c = 0; c < 4; ++c) {
        const int col = wc + c * 16 + l15;
        const int row = wr + r * 16 + lg * 4;
        union { __hip_bfloat16 h[4]; unsigned long long u; } pkv;
#pragma unroll
        for (int i = 0; i < 4; ++i) pkv.h[i] = __float2bfloat16(acc[r][c][i]);
        *(unsigned long long*)(T + col * 136 + row) = pkv.u;
      }
    __syncthreads();
    const int b = m0 >> 11, s0g = m0 & 2047, g = n0 >> 7;
    __hip_bfloat16* Vh = VT + (size_t)(b * 8 + g) * 128 * 2048;
    const int chunk = tid & 15;
#pragma unroll
    for (int it = 0; it < 8; ++it) {
      const int d = it * 16 + (tid >> 4);
      bf16x8 vv = *(const bf16x8*)(T + d * 136 + chunk * 8);
      *(bf16x8*)(Vh + (size_t)d * 2048 + s0g + chunk * 8) = vv;
    }
  }
}

// ---------------- GEMM 256^2 8-phase (T2+T3+T4+T5) for 4096-wide projections --------

__device__ inline int tile_off(int row, int k) {
  return (((row >> 4) << 1) + (k >> 5)) * 512 + (row & 15) * 32 +
         ((k & 31) ^ ((row & 8) << 1));
}

__device__ inline void stageA(const __hip_bfloat16* __restrict__ src, int ld, int row0,
                              int kt, int h, __hip_bfloat16* ldsT, int w, int lane) {
#pragma unroll
  for (int li = 0; li < 2; ++li) {
    const int t = li * 8 + w;
    const int grp = ((t >> 3) << 1) + h;
    const int srl = (t & 7) >> 1, sk = t & 1;
    const int rowbase = grp * 64 + srl * 16;
    __hip_bfloat16* dst = ldsT + ((((rowbase >> 4) << 1) + sk) << 9);
    const int r = lane >> 2;
    const int ku = (lane & 3) ^ ((r & 8) >> 2);
    __builtin_amdgcn_global_load_lds(
        AS1(src + (size_t)(row0 + rowbase + r) * ld + kt + (sk << 5) + (ku << 3)),
        AS3(dst), 16, 0, 0);
  }
}

__device__ inline void stageB(const __hip_bfloat16* __restrict__ src, int ld, int col0,
                              int kt, int h, __hip_bfloat16* ldsT, int w, int lane) {
#pragma unroll
  for (int li = 0; li < 2; ++li) {
    const int t = li * 8 + w;
    const int q = t >> 2;
    const int srl = (t >> 1) & 1, sk = t & 1;
    const int colbase = q * 64 + h * 32 + srl * 16;
    __hip_bfloat16* dst = ldsT + ((((colbase >> 4) << 1) + sk) << 9);
    const int r = lane >> 2;
    const int ku = (lane & 3) ^ ((r & 8) >> 2);
    __builtin_amdgcn_global_load_lds(
        AS1(src + (size_t)(col0 + colbase + r) * ld + kt + (sk << 5) + (ku << 3)),
        AS3(dst), 16, 0, 0);
  }
}

template <int OUT_F32>
__global__ __launch_bounds__(512, 1) void gemm256(const __hip_bfloat16* __restrict__ A,
                                                  const __hip_bfloat16* __restrict__ BT,
                                                  void* __restrict__ Cout,
                                                  int M, int N, int K) {
  __shared__ __align__(16) __hip_bfloat16 lds[2][2][16384];
  const int tid = threadIdx.x;
  const int lane = tid & 63, w = tid >> 6;
  const int l15 = lane & 15, lg = lane >> 4;
  const int wm = w >> 2, wn = w & 3;
  const int nbx = N >> 8;
  const int nwg = (M >> 8) * nbx;
  const int bid = blockIdx.x;
  const int swz = (bid & 7) * (nwg >> 3) + (bid >> 3);
  const int m0 = (swz / nbx) << 8, n0 = (swz % nbx) << 8;

  f32x4 acc[8][4] = {};
  const int NT = K >> 6;

  stageA(A, K, m0, 0, 0, &lds[0][0][0], w, lane);
  stageB(BT, K, n0, 0, 0, &lds[0][1][0], w, lane);
  stageA(A, K, m0, 0, 1, &lds[0][0][0], w, lane);
  stageB(BT, K, n0, 0, 1, &lds[0][1][0], w, lane);
  stageA(A, K, m0, 64, 0, &lds[1][0][0], w, lane);
  stageB(BT, K, n0, 64, 0, &lds[1][1][0], w, lane);
  asm volatile("s_waitcnt vmcnt(4)" ::: "memory");
  __builtin_amdgcn_s_barrier();

  for (int j = 0; j < NT; ++j) {
    const int buf = j & 1;
    const __hip_bfloat16* Ab = &lds[buf][0][0];
    const __hip_bfloat16* Bb = &lds[buf][1][0];
    __hip_bfloat16* An = &lds[buf ^ 1][0][0];
    __hip_bfloat16* Bn = &lds[buf ^ 1][1][0];
    __hip_bfloat16* Ac = &lds[buf][0][0];
    __hip_bfloat16* Bc = &lds[buf][1][0];
    const int kt1 = (j + 1) << 6, kt2 = (j + 2) << 6;
    const bool s1 = (j + 1) < NT, s2 = (j + 2) < NT;

    auto phase = [&](int rq, int cq, int sid) {
      bf16x8 af[2][4], bfr[2][2];
#pragma unroll
      for (int kk = 0; kk < 2; ++kk) {
#pragma unroll
        for (int rf = 0; rf < 4; ++rf)
          af[kk][rf] = *(const bf16x8*)(Ab +
              tile_off(wm * 128 + (rq * 4 + rf) * 16 + l15, kk * 32 + lg * 8));
#pragma unroll
        for (int cf = 0; cf < 2; ++cf)
          bfr[kk][cf] = *(const bf16x8*)(Bb +
              tile_off(wn * 64 + (cq * 2 + cf) * 16 + l15, kk * 32 + lg * 8));
      }
      if (sid == 0)      { if (s1) stageA(A, K, m0, kt1, 1, An, w, lane); }
      else if (sid == 1) { if (s1) stageB(BT, K, n0, kt1, 1, Bn, w, lane); }
      else if (sid == 2) { if (s2) stageA(A, K, m0, kt2, 0, Ac, w, lane); }
      else {
        if (s2) stageB(BT, K, n0, kt2, 0, Bc, w, lane);
        if (s2) asm volatile("s_waitcnt vmcnt(4)" ::: "memory");
        else    asm volatile("s_waitcnt vmcnt(0)" ::: "memory");
      }
      __builtin_amdgcn_s_barrier();
      asm volatile("s_waitcnt lgkmcnt(0)" ::: "memory");
      __builtin_amdgcn_sched_barrier(0);
      __builtin_amdgcn_s_setprio(1);
#pragma unroll
      for (int kk = 0; kk < 2; ++kk)
#pragma unroll
        for (int rf = 0; rf < 4; ++rf)
#pragma unroll
          for (int cf = 0; cf < 2; ++cf)
            acc[rq * 4 + rf][cq * 2 + cf] = __builtin_amdgcn_mfma_f32_16x16x32_bf16(
                af[kk][rf], bfr[kk][cf], acc[rq * 4 + rf][cq * 2 + cf], 0, 0, 0);
      __builtin_amdgcn_s_setprio(0);
      __builtin_amdgcn_s_barrier();
    };
    phase(0, 0, 0);
    phase(0, 1, 1);
    phase(1, 0, 2);
    phase(1, 1, 3);
  }

#pragma unroll
  for (int rf = 0; rf < 8; ++rf)
#pragma unroll
    for (int cf = 0; cf < 4; ++cf)
#pragma unroll
      for (int i = 0; i < 4; ++i) {
        const size_t row = (size_t)(m0 + wm * 128 + rf * 16 + lg * 4 + i);
        const size_t col = (size_t)(n0 + wn * 64 + cf * 16 + l15);
        if (OUT_F32)
          ((float*)Cout)[row * N + col] = acc[rf][cf][i];
        else
          ((__hip_bfloat16*)Cout)[row * N + col] = __float2bfloat16(acc[rf][cf][i]);
      }
}

// ---------------- flash attention (8-warp 32x32, swapped QK^T, in-reg softmax) ------
// RoPE-Q fused into the Q-load (rotate-half partner d<->d+64 is lane-local: kd<->kd+4).
// Softmax VALU cut: v_pk_add/mul_f32 for sum tree + subs + rescale; max3 tree.
__global__ __launch_bounds__(512) void attn(const __hip_bfloat16* __restrict__ Q,
                                            const __hip_bfloat16* __restrict__ Kp,
                                            const __hip_bfloat16* __restrict__ VT,
                                            const int* __restrict__ pos,
                                            __hip_bfloat16* __restrict__ ctx,
                                            float qs) {
  const int tid = threadIdx.x;
  const int lane = tid & 63, w = tid >> 6;
  const int l31 = lane & 31, hi = lane >> 5;
  const int qt = blockIdx.x, h = blockIdx.y, b = blockIdx.z;
  const int kvh = h >> 2;
  const int q0 = qt * 256 + w * 32;

  const __hip_bfloat16* Qh = Q + (size_t)(b * 2048) * 4096 + h * 128;
  const __hip_bfloat16* Kh = Kp + (size_t)(b * 2048) * 1024 + kvh * 128;
  const __hip_bfloat16* Vh = VT + (size_t)(b * 8 + kvh) * 128 * 2048;

  __shared__ __hip_bfloat16 Ks[2][64 * 128];
  __shared__ __hip_bfloat16 Vs[2][128 * 64];

  auto stage = [&](int buf, int s0) {
#pragma unroll
    for (int j = 0; j < 2; ++j) {
      const int idx = w * 64 + lane + j * 512;
      const int rK = idx >> 4, uK = idx & 15;
      __builtin_amdgcn_global_load_lds(
          AS1(Kh + (size_t)(s0 + rK) * 1024 + ((uK ^ (rK & 7)) << 3)),
          AS3(&Ks[buf][(w * 64 + j * 512) * 8]), 16, 0, 0);
      const int rV = idx >> 3, uV = idx & 7;
      __builtin_amdgcn_global_load_lds(
          AS1(Vh + (size_t)rV * 2048 + s0 + ((uV ^ (rV & 7)) << 3)),
          AS3(&Vs[buf][(w * 64 + j * 512) * 8]), 16, 0, 0);
    }
  };

  stage(0, 0);

  // ---- Q load + fused RoPE (per-lane row q0+l31; same math/rounding as old rope) ----
  const int qrow = q0 + l31;
  const float pp = (float)pos[b * 2048 + qrow];
  bf16x8 qf[8];
  {
#pragma unroll
    for (int kd = 0; kd < 4; ++kd) {
      bf16x8 rlo = *(const bf16x8*)(Qh + (size_t)qrow * 4096 + kd * 16 + hi * 8);
      bf16x8 rhi = *(const bf16x8*)(Qh + (size_t)qrow * 4096 + (kd + 4) * 16 + hi * 8);
      bf16x8 olo, ohi;
#pragma unroll
      for (int e = 0; e < 8; ++e) {
        const int j = kd * 16 + hi * 8 + e;
        const float fr = pp * exp2f((float)j * -0.2076205059304601f);
        float sn, cs;
        __sincosf(fr, &sn, &cs);
        const float x0 = __uint_as_float(((unsigned)(unsigned short)rlo[e]) << 16);
        const float x1 = __uint_as_float(((unsigned)(unsigned short)rhi[e]) << 16);
        __hip_bfloat16 h0 = __float2bfloat16((x0 * cs - x1 * sn) * qs);
        __hip_bfloat16 h1 = __float2bfloat16((x1 * cs + x0 * sn) * qs);
        olo[e] = *(short*)&h0;
        ohi[e] = *(short*)&h1;
      }
      qf[kd] = olo;
      qf[kd + 4] = ohi;
    }
  }

  f32x16 o[4] = {};
  float m = -1e30f, lsum = 0.f;
  __syncthreads();

  auto tile = [&](int tt, int cur, bool pf) {
    if (pf) stage(cur ^ 1, (tt + 1) * 64);

    f32x16 p[2] = {};
    __builtin_amdgcn_s_setprio(1);
#pragma unroll
    for (int n = 0; n < 2; ++n)
#pragma unroll
      for (int kd = 0; kd < 8; ++kd) {
        const int row = n * 32 + l31;
        bf16x8 kf = *(const bf16x8*)(&Ks[cur][row * 128 + (((2 * kd + hi) ^ (row & 7)) << 3)]);
        p[n] = __builtin_amdgcn_mfma_f32_32x32x16_bf16(kf, qf[kd], p[n], 0, 0, 0);
      }
    __builtin_amdgcn_s_setprio(0);

    // max tree (max3-fused groupings)
    float t16[16];
#pragma unroll
    for (int e = 0; e < 16; ++e) t16[e] = fmaxf(p[0][e], p[1][e]);
    const float u0 = fmaxf(fmaxf(t16[0], t16[1]), t16[2]);
    const float u1 = fmaxf(fmaxf(t16[3], t16[4]), t16[5]);
    const float u2 = fmaxf(fmaxf(t16[6], t16[7]), t16[8]);
    const float u3 = fmaxf(fmaxf(t16[9], t16[10]), t16[11]);
    const float u4 = fmaxf(fmaxf(t16[12], t16[13]), t16[14]);
    float pmax = fmaxf(fmaxf(fmaxf(u0, u1), u2), fmaxf(fmaxf(u3, u4), t16[15]));
    {
      uint2x r = plswap(__float_as_uint(pmax), __float_as_uint(pmax));
      pmax = fmaxf(__uint_as_float(r[0]), __uint_as_float(r[1]));
    }
    if (!__all(pmax - m <= 8.0f)) {   // defer-max (T13)
      const float mnew = fmaxf(m, pmax);
      const float fac = exp2f(m - mnew);
      m = mnew;
      lsum *= fac;
      f32x2 f2; f2[0] = fac; f2[1] = fac;
#pragma unroll
      for (int dc = 0; dc < 4; ++dc)
#pragma unroll
        for (int i = 0; i < 8; ++i) {
          f32x2 a; a[0] = o[dc][2 * i]; a[1] = o[dc][2 * i + 1];
          a = pkmul(a, f2);
          o[dc][2 * i] = a[0]; o[dc][2 * i + 1] = a[1];
        }
    }
    // packed subtract + exp2
    f32x2 mneg; mneg[0] = -m; mneg[1] = -m;
#pragma unroll
    for (int n = 0; n < 2; ++n)
#pragma unroll
      for (int i = 0; i < 8; ++i) {
        f32x2 a; a[0] = p[n][2 * i]; a[1] = p[n][2 * i + 1];
        a = pkadd(a, mneg);
        p[n][2 * i] = exp2f(a[0]);
        p[n][2 * i + 1] = exp2f(a[1]);
      }
    // packed sum tree
    f32x2 s[8];
#pragma unroll
    for (int i = 0; i < 8; ++i) {
      f32x2 a; a[0] = p[0][2 * i]; a[1] = p[0][2 * i + 1];
      f32x2 bb; bb[0] = p[1][2 * i]; bb[1] = p[1][2 * i + 1];
      s[i] = pkadd(a, bb);
    }
#pragma unroll
    for (int i = 0; i < 4; ++i) s[i] = pkadd(s[i], s[i + 4]);
    s[0] = pkadd(s[0], s[2]);
    s[1] = pkadd(s[1], s[3]);
    s[0] = pkadd(s[0], s[1]);
    float rs = s[0][0] + s[0][1];
    {
      uint2x r = plswap(__float_as_uint(rs), __float_as_uint(rs));
      rs = __uint_as_float(r[0]) + __uint_as_float(r[1]);
    }
    lsum += rs;

    __builtin_amdgcn_s_setprio(1);
#pragma unroll
    for (int n = 0; n < 2; ++n)
#pragma unroll
      for (int ks = 0; ks < 2; ++ks) {
        const int bse = ks * 8;
        unsigned a1 = cvtpk_bf16(p[n][bse + 0], p[n][bse + 1]);
        unsigned b1 = cvtpk_bf16(p[n][bse + 4], p[n][bse + 5]);
        unsigned a2 = cvtpk_bf16(p[n][bse + 2], p[n][bse + 3]);
        unsigned b2 = cvtpk_bf16(p[n][bse + 6], p[n][bse + 7]);
        uint2x s1 = plswap(a1, b1);
        uint2x s2 = plswap(a2, b2);
        union { unsigned u[4]; bf16x8 v; } pw = {{s1[0], s2[0], s1[1], s2[1]}};
        const int slot = n * 2 + ks;
#pragma unroll
        for (int dc = 0; dc < 4; ++dc) {
          const int row = dc * 32 + l31;
          bf16x8 vf = *(const bf16x8*)(&Vs[cur][row * 64 + (((2 * slot + hi) ^ (row & 7)) << 3)]);
          o[dc] = __builtin_amdgcn_mfma_f32_32x32x16_bf16(vf, pw.v, o[dc], 0, 0, 0);
        }
      }
    __builtin_amdgcn_s_setprio(0);
    __syncthreads();
  };

  for (int t2 = 0; t2 < 16; ++t2) {
    tile(2 * t2, 0, true);
    tile(2 * t2 + 1, 1, t2 < 15);
  }

  const float inv = 1.0f / lsum;
  const size_t rowbase = ((size_t)(b * 2048 + q0 + l31)) * 4096 + h * 128;
#pragma unroll
  for (int dc = 0; dc < 4; ++dc)
#pragma unroll
    for (int g = 0; g < 4; ++g) {
      union { unsigned short us[4]; ushort4 u4; } pk;
#pragma unroll
      for (int e = 0; e < 4; ++e) {
        __hip_bfloat16 hv = __float2bfloat16(o[dc][g * 4 + e] * inv);
        pk.us[e] = *(unsigned short*)&hv;
      }
      *(ushort4*)(ctx + rowbase + dc * 32 + g * 8 + hi * 4) = pk.u4;
    }
}

// ---------------- launcher ----------------

extern "C" void kernel_launch(void* const* d_in, const int* in_sizes, int n_in,
                              void* d_out, int out_size, void* d_ws, size_t ws_size,
                              hipStream_t stream) {
  const float* q_in = (const float*)d_in[0];
  const float* k_in = (const float*)d_in[1];
  const float* v_in = (const float*)d_in[2];
  const int* pos    = (const int*)d_in[3];
  const float* Wq   = (const float*)d_in[4];
  const float* Wk   = (const float*)d_in[5];
  const float* Wv   = (const float*)d_in[6];
  const float* Wo   = (const float*)d_in[7];

  char* ws = (char*)d_ws;
  __hip_bfloat16* xbuf = (__hip_bfloat16*)(ws);              // qconv -> kconv -> ctx
  __hip_bfloat16* WqT  = (__hip_bfloat16*)(ws + 33554432);   // WqT -> vconv
  __hip_bfloat16* WkT  = (__hip_bfloat16*)(ws + 67108864);
  __hip_bfloat16* WvT  = (__hip_bfloat16*)(ws + 75497472);
  __hip_bfloat16* WoT  = (__hip_bfloat16*)(ws + 83886080);
  __hip_bfloat16* Qp   = (__hip_bfloat16*)(ws + 117440512);
  __hip_bfloat16* Kp   = (__hip_bfloat16*)(ws + 150994944);
  __hip_bfloat16* VTb  = (__hip_bfloat16*)(ws + 167772160);
  __hip_bfloat16* vconv = WqT;  // WqT dead after gemm256-Q

  // 1) all weight transposes (one launch)
  wtransAll<<<dim3(128, 128, 4), dim3(32, 8), 0, stream>>>(Wq, Wo, Wk, Wv,
                                                           WqT, WoT, WkT, WvT);
  // 2) Q path (Q written unroped; RoPE+scale fused into attn's Q-load)
  xconv<<<16384, 256, 0, stream>>>(q_in, xbuf);
  gemm256<0><<<256, 512, 0, stream>>>(xbuf, WqT, Qp, 4096, 4096, 4096);
  // 3) K+V conversions
  xconv_kv<<<dim3(16384, 2), 256, 0, stream>>>(k_in, v_in, xbuf, vconv);
  // 4) fused K+V projection; V epilogue writes VT directly
  gemm_kv<<<dim3(8, 32, 2), 256, 0, stream>>>(xbuf, vconv, WkT, WvT, Kp, VTb);
  // 5) RoPE on K only
  rope<<<8192, 256, 0, stream>>>(Kp, pos, 3, 1.0f);
  // 6) attention -> ctx (fused RoPE-Q; reuses xbuf)
  attn<<<dim3(8, 32, 2), 512, 0, stream>>>(Qp, Kp, VTb, pos, xbuf,
                                           0.08838834764831845f * 1.4426950408889634f);
  // 7) output projection, f32 epilogue straight to d_out
  gemm256<1><<<256, 512, 0, stream>>>(xbuf, WoT, d_out, 4096, 4096, 4096);
}